// Round 10
// baseline (234.416 us; speedup 1.0000x reference)
//
#include <hip/hip_runtime.h>
#include <hip/hip_bf16.h>
#include <cstdint>
#include <cstddef>

typedef __bf16 bf16x8 __attribute__((ext_vector_type(8)));
typedef __bf16 bf16x4 __attribute__((ext_vector_type(4)));
typedef __bf16 bf16x2 __attribute__((ext_vector_type(2)));
typedef float  f32x4  __attribute__((ext_vector_type(4)));

static constexpr int TSEQ  = 2048;
static constexpr int DM    = 1024;
static constexpr int NH    = 16;
static constexpr int HD    = 64;
static constexpr int BATCH = 4;
// exp(s/8) = 2^(s * log2(e)/8)
static constexpr float SCL = 0.18033688011112042f;

// async global->LDS, 16B per lane; LDS dest is wave-uniform base + lane*16
__device__ __forceinline__ void gload16(const __bf16* g, __bf16* l) {
  __builtin_amdgcn_global_load_lds((const __attribute__((address_space(1))) void*)g,
                                   (__attribute__((address_space(3))) void*)l, 16, 0, 0);
}

#define PBAR()   asm volatile("s_barrier" ::: "memory")
#define LGKMN(n) asm volatile("s_waitcnt lgkmcnt(" #n ")" ::: "memory")

// ---------------- fp32 -> bf16 convert ----------------
__global__ __launch_bounds__(256) void cvt_kernel(const float* __restrict__ in,
                                                  __bf16* __restrict__ out, int n4) {
  int i = blockIdx.x * 256 + threadIdx.x;
  if (i < n4) {
    float4 v = reinterpret_cast<const float4*>(in)[i];
    bf16x4 o;
    o[0] = (__bf16)v.x; o[1] = (__bf16)v.y; o[2] = (__bf16)v.z; o[3] = (__bf16)v.w;
    reinterpret_cast<bf16x4*>(out)[i] = o;
  }
}

// 4 weight matrices in one launch (blockIdx.y selects)
__global__ __launch_bounds__(256) void cvt4_kernel(
    const float* __restrict__ a, const float* __restrict__ bsrc,
    const float* __restrict__ c, const float* __restrict__ d,
    __bf16* __restrict__ oa, __bf16* __restrict__ ob,
    __bf16* __restrict__ oc, __bf16* __restrict__ od, int n4) {
  const float* src = (blockIdx.y == 0) ? a : (blockIdx.y == 1) ? bsrc
                    : (blockIdx.y == 2) ? c : d;
  __bf16* dst = (blockIdx.y == 0) ? oa : (blockIdx.y == 1) ? ob
               : (blockIdx.y == 2) ? oc : od;
  int i = blockIdx.x * 256 + threadIdx.x;
  if (i < n4) {
    float4 v = reinterpret_cast<const float4*>(src)[i];
    bf16x4 o;
    o[0] = (__bf16)v.x; o[1] = (__bf16)v.y; o[2] = (__bf16)v.z; o[3] = (__bf16)v.w;
    reinterpret_cast<bf16x4*>(dst)[i] = o;
  }
}

// ---------------- QKV GEMM body: 256x256, BK=64, 8 waves, pipelined 4-phase ----------------
// Same schedule as R9; R10 change is ONLY the launch bound on gemm_qkv_kernel
// ((512,2) -> (512)): LDS already caps at 1 block/CU, the ,2 clause only imposed
// a 128-VGPR cap that spilled this schedule's ~180-reg live set (R9: WRITE_SIZE
// +40MB scratch stores). First arg alone caps at 256 VGPR = 2 waves/SIMD budget.
template <typename OUT_T>
__device__ __forceinline__ void gemm_body8(
    const __bf16* __restrict__ A, const __bf16* __restrict__ W,
    const float* __restrict__ bias, OUT_T* __restrict__ C,
    int i0, int o0, __bf16* lA, __bf16* lB) {
  const int tid = threadIdx.x;          // 0..511
  const int l = tid & 63, lr = l & 15, lg = l >> 4;
  const int w = tid >> 6;
  const int wr = w >> 2, wc = w & 3;    // wave tile: rows wr*128, cols wc*64

  f32x4 acc[8][4];
  const f32x4 fzero = {0.f, 0.f, 0.f, 0.f};
#pragma unroll
  for (int mi = 0; mi < 8; ++mi)
#pragma unroll
    for (int ni = 0; ni < 4; ++ni) acc[mi][ni] = fzero;

  const int s_row = tid >> 3;           // 0..63
  const int s_cc  = tid & 7;
  const __bf16* Ab = A + (size_t)i0 * DM;
  const __bf16* Wb = W + (size_t)o0 * DM;

  auto stage = [&](const __bf16* G, __bf16* L, int buf, int kt, int h) {
#pragma unroll
    for (int rr = 0; rr < 2; ++rr) {
      int row = h * 128 + rr * 64 + s_row;
      gload16(G + (size_t)row * DM + kt * 64 + ((s_cc ^ (row & 7)) << 3),
              L + buf * 16384 + (h * 128 + rr * 64) * 64 + tid * 8);
    }
  };
  auto rd = [&](const __bf16* base, int row, int ks) {
    int chunk = (ks * 4 + lg) ^ (row & 7);
    return *(const bf16x8*)(base + row * 64 + chunk * 8);
  };

  const int NT = DM / 64;               // 16 K-tiles

  // prologue: tiles 0,1 fully staged; wait tile 0; initial afl/bfl reads
#pragma unroll
  for (int h = 0; h < 2; ++h) { stage(Ab, lA, 0, 0, h); stage(Wb, lB, 0, 0, h); }
#pragma unroll
  for (int h = 0; h < 2; ++h) { stage(Ab, lA, 1, 1, h); stage(Wb, lB, 1, 1, h); }
  asm volatile("s_waitcnt vmcnt(8)" ::: "memory");
  PBAR();

  bf16x8 afl[4][2], afh[4][2], bfl[2][2], bfh[2][2];
#pragma unroll
  for (int mi = 0; mi < 4; ++mi)
#pragma unroll
    for (int ks = 0; ks < 2; ++ks)
      afl[mi][ks] = rd(lA, wr * 128 + mi * 16 + lr, ks);
#pragma unroll
  for (int ni = 0; ni < 2; ++ni)
#pragma unroll
    for (int ks = 0; ks < 2; ++ks)
      bfl[ni][ks] = rd(lB, wc * 64 + ni * 16 + lr, ks);

  for (int t = 0; t < NT; ++t) {
    const int cur = t & 1;
    const __bf16* cA = lA + cur * 16384;
    const __bf16* cB = lB + cur * 16384;
    const __bf16* nA = lA + (cur ^ 1) * 16384;
    const __bf16* nB = lB + (cur ^ 1) * 16384;
    const bool pre = (t + 2 < NT);
    const bool hasnext = (t + 1 < NT);

    // ---- phase 1: Q1 = mi0-3 x ni0-1 ----
#pragma unroll
    for (int ni = 0; ni < 2; ++ni)
#pragma unroll
      for (int ks = 0; ks < 2; ++ks)
        bfh[ni][ks] = rd(cB, wc * 64 + (ni + 2) * 16 + lr, ks);
    PBAR(); LGKMN(4);
    __builtin_amdgcn_s_setprio(1);
#pragma unroll
    for (int mi = 0; mi < 4; ++mi)
#pragma unroll
      for (int ni = 0; ni < 2; ++ni)
#pragma unroll
        for (int ks = 0; ks < 2; ++ks)
          acc[mi][ni] = __builtin_amdgcn_mfma_f32_16x16x32_bf16(
              afl[mi][ks], bfl[ni][ks], acc[mi][ni], 0, 0, 0);
    __builtin_amdgcn_s_setprio(0);
    PBAR();

    // ---- phase 2: Q2 = mi0-3 x ni2-3; stage Bh0(t+2) ----
#pragma unroll
    for (int mi = 0; mi < 4; ++mi)
#pragma unroll
      for (int ks = 0; ks < 2; ++ks)
        afh[mi][ks] = rd(cA, wr * 128 + (mi + 4) * 16 + lr, ks);
    if (pre) stage(Wb, lB, cur, t + 2, 0);
    PBAR(); LGKMN(8);
    __builtin_amdgcn_s_setprio(1);
#pragma unroll
    for (int mi = 0; mi < 4; ++mi)
#pragma unroll
      for (int ni = 0; ni < 2; ++ni)
#pragma unroll
        for (int ks = 0; ks < 2; ++ks)
          acc[mi][ni + 2] = __builtin_amdgcn_mfma_f32_16x16x32_bf16(
              afl[mi][ks], bfh[ni][ks], acc[mi][ni + 2], 0, 0, 0);
    __builtin_amdgcn_s_setprio(0);
    PBAR();

    // ---- phase 3: Q3 = mi4-7 x ni0-1; stage Bh1,Ah0(t+2) ----
    if (pre) { stage(Wb, lB, cur, t + 2, 1); stage(Ab, lA, cur, t + 2, 0); }
    PBAR(); LGKMN(0);
    __builtin_amdgcn_s_setprio(1);
#pragma unroll
    for (int mi = 0; mi < 4; ++mi)
#pragma unroll
      for (int ni = 0; ni < 2; ++ni)
#pragma unroll
        for (int ks = 0; ks < 2; ++ks)
          acc[mi + 4][ni] = __builtin_amdgcn_mfma_f32_16x16x32_bf16(
              afh[mi][ks], bfl[ni][ks], acc[mi + 4][ni], 0, 0, 0);
    __builtin_amdgcn_s_setprio(0);
    PBAR();

    // ---- phase 4: Q4 = mi4-7 x ni2-3; stage Ah1(t+2); vmcnt; read t+1 afl/bfl ----
    if (pre) stage(Ab, lA, cur, t + 2, 1);
    if (pre)             asm volatile("s_waitcnt vmcnt(8)" ::: "memory");
    else if (hasnext)    asm volatile("s_waitcnt vmcnt(0)" ::: "memory");
    PBAR();
    if (hasnext) {
      // refill afl/bfl (dead since Q2/Q3) with tile t+1's fragments; Q4 has no
      // register dependence on these loads -> they land under Q4 + next ph1 bar.
#pragma unroll
      for (int mi = 0; mi < 4; ++mi)
#pragma unroll
        for (int ks = 0; ks < 2; ++ks)
          afl[mi][ks] = rd(nA, wr * 128 + mi * 16 + lr, ks);
#pragma unroll
      for (int ni = 0; ni < 2; ++ni)
#pragma unroll
        for (int ks = 0; ks < 2; ++ks)
          bfl[ni][ks] = rd(nB, wc * 64 + ni * 16 + lr, ks);
    }
    __builtin_amdgcn_s_setprio(1);
#pragma unroll
    for (int mi = 0; mi < 4; ++mi)
#pragma unroll
      for (int ni = 0; ni < 2; ++ni)
#pragma unroll
        for (int ks = 0; ks < 2; ++ks)
          acc[mi + 4][ni + 2] = __builtin_amdgcn_mfma_f32_16x16x32_bf16(
              afh[mi][ks], bfh[ni][ks], acc[mi + 4][ni + 2], 0, 0, 0);
    __builtin_amdgcn_s_setprio(0);
    PBAR();
  }

#pragma unroll
  for (int ni = 0; ni < 4; ++ni) {
    int col = o0 + wc * 64 + ni * 16 + lr;
    float bb = bias[col];
#pragma unroll
    for (int mi = 0; mi < 8; ++mi) {
      int row = i0 + wr * 128 + mi * 16 + lg * 4;
#pragma unroll
      for (int r = 0; r < 4; ++r)
        C[(size_t)(row + r) * DM + col] = (OUT_T)(acc[mi][ni][r] + bb);
    }
  }
}

// QKV fused over N=3072: grid 384 = 32 mi * 12 nig (256x256 tiles), XCD-grouped.
// NOTE: launch bound (512) only — LDS caps occupancy at 1 block/CU already;
// adding ",2" would re-impose the 128-VGPR cap that spilled in R9.
__global__ __launch_bounds__(512) void gemm_qkv_kernel(
    const __bf16* __restrict__ A,
    const __bf16* __restrict__ W0, const __bf16* __restrict__ W1,
    const __bf16* __restrict__ W2,
    const float* __restrict__ b0, const float* __restrict__ b1,
    const float* __restrict__ b2,
    __bf16* __restrict__ O0, __bf16* __restrict__ O1, __bf16* __restrict__ O2) {
  __shared__ __align__(16) __bf16 lA[2 * 256 * 64];
  __shared__ __align__(16) __bf16 lB[2 * 256 * 64];
  const int flat = blockIdx.x;
  const int xcd = flat & 7, idx = flat >> 3;       // idx 0..47
  const int mi = xcd * 4 + idx / 12;               // 0..31
  const int nig = idx % 12;                        // 0..11
  const int z = nig >> 2;
  const int o0 = (nig & 3) * 256;
  const __bf16* W = (z == 0) ? W0 : (z == 1) ? W1 : W2;
  const float* bias = (z == 0) ? b0 : (z == 1) ? b1 : b2;
  __bf16* C = (z == 0) ? O0 : (z == 1) ? O1 : O2;
  gemm_body8<__bf16>(A, W, bias, C, mi * 256, o0, lA, lB);
}

// ---------------- out-proj GEMM: 128x256 tile (R4 body), grid 256 ----------------
template <typename OUT_T>
__device__ __forceinline__ void gemm_body2(
    const __bf16* __restrict__ A, const __bf16* __restrict__ W,
    const float* __restrict__ bias, OUT_T* __restrict__ C,
    int i0, int o0, __bf16* lA, __bf16* lB) {
  const int tid = threadIdx.x;          // 0..511
  const int l = tid & 63, lr = l & 15, lg = l >> 4;
  const int w = tid >> 6;
  const int wr = w >> 2, wc = w & 3;

  f32x4 acc[4][4];
  const f32x4 fzero = {0.f, 0.f, 0.f, 0.f};
#pragma unroll
  for (int mi = 0; mi < 4; ++mi)
#pragma unroll
    for (int ni = 0; ni < 4; ++ni) acc[mi][ni] = fzero;

  const int s_row = tid >> 3;
  const int s_cc  = tid & 7;
  const int NT = DM / 64;  // 16

  {
#pragma unroll
    for (int n = 0; n < 2; ++n) {
      int row = n * 64 + s_row;
      gload16(A + (size_t)(i0 + row) * DM + ((s_cc ^ (row & 7)) << 3),
              lA + n * 4096 + tid * 8);
    }
#pragma unroll
    for (int n = 0; n < 4; ++n) {
      int row = n * 64 + s_row;
      gload16(W + (size_t)(o0 + row) * DM + ((s_cc ^ (row & 7)) << 3),
              lB + n * 4096 + tid * 8);
    }
  }
  asm volatile("s_waitcnt vmcnt(0)" ::: "memory");
  __syncthreads();

  for (int t = 0; t < NT; ++t) {
    const int cur = t & 1;
    if (t + 1 < NT) {
      const int k0 = (t + 1) * 64;
      const int nxt = cur ^ 1;
#pragma unroll
      for (int n = 0; n < 2; ++n) {
        int row = n * 64 + s_row;
        gload16(A + (size_t)(i0 + row) * DM + k0 + ((s_cc ^ (row & 7)) << 3),
                lA + nxt * 8192 + n * 4096 + tid * 8);
      }
#pragma unroll
      for (int n = 0; n < 4; ++n) {
        int row = n * 64 + s_row;
        gload16(W + (size_t)(o0 + row) * DM + k0 + ((s_cc ^ (row & 7)) << 3),
                lB + nxt * 16384 + n * 4096 + tid * 8);
      }
    }

    const __bf16* cA = lA + cur * 8192;
    const __bf16* cB = lB + cur * 16384;

    bf16x8 af[4][2], bf_[2][2];
#pragma unroll
    for (int mi = 0; mi < 4; ++mi)
#pragma unroll
      for (int ks = 0; ks < 2; ++ks) {
        int row = wr * 64 + mi * 16 + lr;
        int chunk = (ks * 4 + lg) ^ (row & 7);
        af[mi][ks] = *(const bf16x8*)(cA + row * 64 + chunk * 8);
      }
#pragma unroll
    for (int ni = 0; ni < 2; ++ni)
#pragma unroll
      for (int ks = 0; ks < 2; ++ks) {
        int row = wc * 64 + ni * 16 + lr;
        int chunk = (ks * 4 + lg) ^ (row & 7);
        bf_[ni][ks] = *(const bf16x8*)(cB + row * 64 + chunk * 8);
      }
    __builtin_amdgcn_s_setprio(1);
#pragma unroll
    for (int mi = 0; mi < 4; ++mi)
#pragma unroll
      for (int ni = 0; ni < 2; ++ni)
#pragma unroll
        for (int ks = 0; ks < 2; ++ks)
          acc[mi][ni] = __builtin_amdgcn_mfma_f32_16x16x32_bf16(
              af[mi][ks], bf_[ni][ks], acc[mi][ni], 0, 0, 0);
    __builtin_amdgcn_s_setprio(0);

#pragma unroll
    for (int ni = 0; ni < 2; ++ni)
#pragma unroll
      for (int ks = 0; ks < 2; ++ks) {
        int row = wc * 64 + (ni + 2) * 16 + lr;
        int chunk = (ks * 4 + lg) ^ (row & 7);
        bf_[ni][ks] = *(const bf16x8*)(cB + row * 64 + chunk * 8);
      }
    __builtin_amdgcn_s_setprio(1);
#pragma unroll
    for (int mi = 0; mi < 4; ++mi)
#pragma unroll
      for (int ni = 0; ni < 2; ++ni)
#pragma unroll
        for (int ks = 0; ks < 2; ++ks)
          acc[mi][ni + 2] = __builtin_amdgcn_mfma_f32_16x16x32_bf16(
              af[mi][ks], bf_[ni][ks], acc[mi][ni + 2], 0, 0, 0);
    __builtin_amdgcn_s_setprio(0);

    if (t + 1 < NT) {
      asm volatile("s_waitcnt vmcnt(0)" ::: "memory");
      __syncthreads();
    }
  }

#pragma unroll
  for (int ni = 0; ni < 4; ++ni) {
    int col = o0 + wc * 64 + ni * 16 + lr;
    float bb = bias[col];
#pragma unroll
    for (int mi = 0; mi < 4; ++mi) {
      int row = i0 + wr * 64 + mi * 16 + lg * 4;
#pragma unroll
      for (int r = 0; r < 4; ++r)
        C[(size_t)(row + r) * DM + col] = (OUT_T)(acc[mi][ni][r] + bb);
    }
  }
}

// Output GEMM: grid 256 = 64 mi * 4 ni (exactly 1 block/CU), XCD-grouped.
__global__ __launch_bounds__(512, 2) void gemm_out_kernel(
    const __bf16* __restrict__ A, const __bf16* __restrict__ W,
    const float* __restrict__ bias, float* __restrict__ C) {
  __shared__ __align__(16) __bf16 lA[2 * 128 * 64];
  __shared__ __align__(16) __bf16 lB[2 * 256 * 64];
  const int flat = blockIdx.x;
  const int xcd = flat & 7, idx = flat >> 3;       // idx 0..31
  const int mi = xcd * 8 + (idx & 7);              // 0..63
  const int ni = idx >> 3;                         // 0..3
  gemm_body2<float>(A, W, bias, C, mi * 128, ni * 256, lA, lB);
}

// ---------------- pass B: column sums c[k] = sum_{q>=k} exp(s[q,k]); VT = V^T / c ----------------
// flat grid 1024; XCD-grouped; k-tile pairing {bx, 31-bx} -> constant work.
__global__ __launch_bounds__(256) void colstats_kernel(
    const __bf16* __restrict__ Q, const __bf16* __restrict__ K,
    const __bf16* __restrict__ V, __bf16* __restrict__ VT) {
  const int flat = blockIdx.x;
  const int wid = (flat & 7) * 128 + (flat >> 3);  // 0..1023
  const int g = wid >> 4, bx = wid & 15;
  const int h = g & 15, b = g >> 4;
  const int tid = threadIdx.x;
  const int w = tid >> 6, l = tid & 63, lr = l & 15, lg = l >> 4;
  const size_t base = (size_t)b * TSEQ * DM + (size_t)h * HD;

  __shared__ float part[4][64];
  __shared__ float invc[64];

  for (int ph = 0; ph < 2; ++ph) {
    const int kt = ph ? (31 - bx) : bx;
    const int k0 = kt * 64;

    bf16x8 kf[4][2];
#pragma unroll
    for (int ct = 0; ct < 4; ++ct)
#pragma unroll
      for (int ks = 0; ks < 2; ++ks)
        kf[ct][ks] = *(const bf16x8*)(K + base + (size_t)(k0 + ct * 16 + lr) * DM +
                                      ks * 32 + lg * 8);

    float csum[4] = {0.f, 0.f, 0.f, 0.f};
    const int nchunks = (TSEQ - k0) >> 4;  // >= 4 always
    for (int jj = w; jj < nchunks; jj += 4) {
      int qrow = k0 + jj * 16;
      bf16x8 a0 = *(const bf16x8*)(Q + base + (size_t)(qrow + lr) * DM + lg * 8);
      bf16x8 a1 = *(const bf16x8*)(Q + base + (size_t)(qrow + lr) * DM + 32 + lg * 8);
      const bool interior = (jj >= 4);  // whole chunk strictly below diagonal band
#pragma unroll
      for (int ct = 0; ct < 4; ++ct) {
        f32x4 s = {0.f, 0.f, 0.f, 0.f};
        s = __builtin_amdgcn_mfma_f32_16x16x32_bf16(a0, kf[ct][0], s, 0, 0, 0);
        s = __builtin_amdgcn_mfma_f32_16x16x32_bf16(a1, kf[ct][1], s, 0, 0, 0);
        if (interior) {
#pragma unroll
          for (int r = 0; r < 4; ++r) csum[ct] += __builtin_amdgcn_exp2f(s[r] * SCL);
        } else {
#pragma unroll
          for (int r = 0; r < 4; ++r) {
            int ql = jj * 16 + lg * 4 + r;
            int kl = ct * 16 + lr;
            float e = __builtin_amdgcn_exp2f(s[r] * SCL);
            csum[ct] += (ql >= kl) ? e : 0.f;
          }
        }
      }
    }

#pragma unroll
    for (int ct = 0; ct < 4; ++ct) {
      csum[ct] += __shfl_xor(csum[ct], 16, 64);
      csum[ct] += __shfl_xor(csum[ct], 32, 64);
    }

    if (l < 16) {
#pragma unroll
      for (int ct = 0; ct < 4; ++ct) part[w][ct * 16 + l] = csum[ct];
    }
    __syncthreads();
    if (tid < 64) {
      float c = part[0][tid] + part[1][tid] + part[2][tid] + part[3][tid];
      invc[tid] = 1.0f / c;
    }
    __syncthreads();

    // VT[b,h][d][k] = V[k][d] * invc ; thread t: d = t>>2, k-cols (t&3)*16..+15
    const int d = tid >> 2, gq = tid & 3;
    size_t vtb = (((size_t)(b * NH + h)) * HD + d) * TSEQ + k0 + gq * 16;
#pragma unroll
    for (int kc = 0; kc < 16; kc += 2) {
      int kl = gq * 16 + kc;
      float v0 = (float)V[base + (size_t)(k0 + kl) * DM + d] * invc[kl];
      float v1 = (float)V[base + (size_t)(k0 + kl + 1) * DM + d] * invc[kl + 1];
      bf16x2 o; o[0] = (__bf16)v0; o[1] = (__bf16)v1;
      *(bf16x2*)(VT + vtb + kc) = o;
    }
    __syncthreads();  // part/invc reuse safety across phases
  }
}

// XOR swizzle (involution) on element index of a [64][64] bf16 tile
__device__ __forceinline__ int swz(int e) { return e ^ (((e >> 6) & 7) << 3); }

// ---------------- pass C (FUSED): both q-tiles {31-bx, bx} in ONE K-loop ----------------
// Single-buffered (TLP covers latency: 39KB LDS -> 4 blocks/CU = 16 waves).
// Per staged K-tile: kb8/vb8 read ONCE, feed both tiles' MFMAs.
__global__ __launch_bounds__(256, 4) void ctx_kernel(
    const __bf16* __restrict__ Q, const __bf16* __restrict__ K,
    const __bf16* __restrict__ VT, __bf16* __restrict__ CTX) {
  __shared__ __align__(16) __bf16 lK[4096];
  __shared__ __align__(16) __bf16 lV[4096];
  __shared__ __align__(16) __bf16 lP[8][16 * 88];   // [wave + 4*tile]
  const int flat = blockIdx.x;
  const int wid = (flat & 7) * 128 + (flat >> 3);  // 0..1023
  const int g = wid >> 4, bx = wid & 15;
  const int h = g & 15, b = g >> 4;
  const int tid = threadIdx.x;
  const int w = tid >> 6, l = tid & 63, lr = l & 15, lg = l >> 4;
  const size_t base = (size_t)b * TSEQ * DM + (size_t)h * HD;
  const size_t vtb = ((size_t)(b * NH + h)) * HD * TSEQ;
  __bf16* pw1 = &lP[w][0];
  __bf16* pw2 = &lP[w + 4][0];

  const int qt1 = 31 - bx, qt2 = bx;   // qt1 >= 16 > qt2 always
  const int q01 = qt1 * 64, q02 = qt2 * 64;

  const int srow = w * 8 + (l >> 3);
  const int scol = (((l & 7) ^ (l >> 3)) << 3);

  bf16x8 qf1[2], qf2[2];
#pragma unroll
  for (int ks = 0; ks < 2; ++ks) {
    qf1[ks] = *(const bf16x8*)(Q + base + (size_t)(q01 + w * 16 + lr) * DM + ks * 32 + lg * 8);
    qf2[ks] = *(const bf16x8*)(Q + base + (size_t)(q02 + w * 16 + lr) * DM + ks * 32 + lg * 8);
  }

  f32x4 acc1[4], acc2[4];
  const f32x4 fzero = {0.f, 0.f, 0.f, 0.f};
#pragma unroll
  for (int dt = 0; dt < 4; ++dt) { acc1[dt] = fzero; acc2[dt] = fzero; }

  for (int kt = 0; kt <= qt1; ++kt) {
    const int k0 = kt * 64;
    const bool two = (kt <= qt2);
    __syncthreads();   // prior iter's LDS reads done before overwrite
#pragma unroll
    for (int n = 0; n < 2; ++n) {
      gload16(K + base + (size_t)(k0 + n * 32 + srow) * DM + scol,
              lK + n * 2048 + w * 512);
      gload16(VT + vtb + (size_t)(n * 32 + srow) * TSEQ + k0 + scol,
              lV + n * 2048 + w * 512);
    }
    asm volatile("s_waitcnt vmcnt(0)" ::: "memory");
    __syncthreads();

    const bool diag1 = (kt == qt1), diag2 = (kt == qt2);
#pragma unroll
    for (int ct = 0; ct < 4; ++ct) {
      bf16x8 kb[2];
#pragma unroll
      for (int ks = 0; ks < 2; ++ks) {
        int e = (ct * 16 + lr) * 64 + ks * 32 + lg * 8;
        kb[ks] = *(const bf16x8*)(lK + swz(e));
      }
      {
        f32x4 s = {0.f, 0.f, 0.f, 0.f};
        s = __builtin_amdgcn_mfma_f32_16x16x32_bf16(kb[0], qf1[0], s, 0, 0, 0);
        s = __builtin_amdgcn_mfma_f32_16x16x32_bf16(kb[1], qf1[1], s, 0, 0, 0);
        bf16x4 pk;
        if (diag1) {
#pragma unroll
          for (int r = 0; r < 4; ++r) {
            int ql = w * 16 + lr, kl = ct * 16 + lg * 4 + r;
            pk[r] = (__bf16)((ql >= kl) ? __builtin_amdgcn_exp2f(s[r] * SCL) : 0.f);
          }
        } else {
#pragma unroll
          for (int r = 0; r < 4; ++r)
            pk[r] = (__bf16)__builtin_amdgcn_exp2f(s[r] * SCL);
        }
        *(bf16x4*)(pw1 + lr * 88 + ct * 16 + lg * 4) = pk;
      }
      if (two) {
        f32x4 s = {0.f, 0.f, 0.f, 0.f};
        s = __builtin_amdgcn_mfma_f32_16x16x32_bf16(kb[0], qf2[0], s, 0, 0, 0);
        s = __builtin_amdgcn_mfma_f32_16x16x32_bf16(kb[1], qf2[1], s, 0, 0, 0);
        bf16x4 pk;
        if (diag2) {
#pragma unroll
          for (int r = 0; r < 4; ++r) {
            int ql = w * 16 + lr, kl = ct * 16 + lg * 4 + r;
            pk[r] = (__bf16)((ql >= kl) ? __builtin_amdgcn_exp2f(s[r] * SCL) : 0.f);
          }
        } else {
#pragma unroll
          for (int r = 0; r < 4; ++r)
            pk[r] = (__bf16)__builtin_amdgcn_exp2f(s[r] * SCL);
        }
        *(bf16x4*)(pw2 + lr * 88 + ct * 16 + lg * 4) = pk;
      }
    }
    asm volatile("" ::: "memory");  // same-wave DS in-order: P writes before reads

    bf16x8 pa1[2], pa2[2];
#pragma unroll
    for (int ks = 0; ks < 2; ++ks)
      pa1[ks] = *(const bf16x8*)(pw1 + lr * 88 + ks * 32 + lg * 8);
    if (two) {
#pragma unroll
      for (int ks = 0; ks < 2; ++ks)
        pa2[ks] = *(const bf16x8*)(pw2 + lr * 88 + ks * 32 + lg * 8);
    }
#pragma unroll
    for (int dt = 0; dt < 4; ++dt) {
#pragma unroll
      for (int ks = 0; ks < 2; ++ks) {
        int e = (dt * 16 + lr) * 64 + ks * 32 + lg * 8;
        bf16x8 vb8 = *(const bf16x8*)(lV + swz(e));   // shared by both tiles
        acc1[dt] = __builtin_amdgcn_mfma_f32_16x16x32_bf16(pa1[ks], vb8, acc1[dt], 0, 0, 0);
        if (two)
          acc2[dt] = __builtin_amdgcn_mfma_f32_16x16x32_bf16(pa2[ks], vb8, acc2[dt], 0, 0, 0);
      }
    }
  }

#pragma unroll
  for (int dt = 0; dt < 4; ++dt)
#pragma unroll
    for (int r = 0; r < 4; ++r) {
      CTX[base + (size_t)(q01 + w * 16 + lg * 4 + r) * DM + dt * 16 + lr] = (__bf16)acc1[dt][r];
      CTX[base + (size_t)(q02 + w * 16 + lg * 4 + r) * DM + dt * 16 + lr] = (__bf16)acc2[dt][r];
    }
}

extern "C" void kernel_launch(void* const* d_in, const int* in_sizes, int n_in,
                              void* d_out, int out_size, void* d_ws, size_t ws_size,
                              hipStream_t stream) {
  const float* q  = (const float*)d_in[0];
  const float* Wq = (const float*)d_in[3];
  const float* bq = (const float*)d_in[4];
  const float* Wk = (const float*)d_in[5];
  const float* bk = (const float*)d_in[6];
  const float* Wv = (const float*)d_in[7];
  const float* bv = (const float*)d_in[8];
  const float* Wo = (const float*)d_in[9];
  const float* bo = (const float*)d_in[10];
  float* out = (float*)d_out;

  const size_t NTOK = (size_t)BATCH * TSEQ;  // 8192
  char* ws = (char*)d_ws;
  __bf16* qb  = (__bf16*)ws; ws += NTOK * DM * 2;   // reused as CTX after QKV GEMMs
  __bf16* Wqb = (__bf16*)ws; ws += (size_t)DM * DM * 2;
  __bf16* Wkb = (__bf16*)ws; ws += (size_t)DM * DM * 2;
  __bf16* Wvb = (__bf16*)ws; ws += (size_t)DM * DM * 2;
  __bf16* Wob = (__bf16*)ws; ws += (size_t)DM * DM * 2;
  __bf16* Qp  = (__bf16*)ws; ws += NTOK * DM * 2;
  __bf16* Kp  = (__bf16*)ws; ws += NTOK * DM * 2;
  __bf16* Vp  = (__bf16*)ws; ws += NTOK * DM * 2;
  __bf16* VT  = (__bf16*)ws; ws += (size_t)BATCH * NH * HD * TSEQ * 2;
  __bf16* CTX = qb;  // qb dead after the QKV GEMMs

  const int nq4 = (int)(NTOK * DM / 4);
  const int nw4 = DM * DM / 4;
  cvt_kernel<<<(nq4 + 255) / 256, 256, 0, stream>>>(q, qb, nq4);
  cvt4_kernel<<<dim3((nw4 + 255) / 256, 4), 256, 0, stream>>>(
      Wq, Wk, Wv, Wo, Wqb, Wkb, Wvb, Wob, nw4);

  gemm_qkv_kernel<<<384, 512, 0, stream>>>(qb, Wqb, Wkb, Wvb, bq, bk, bv,
                                           Qp, Kp, Vp);

  colstats_kernel<<<1024, 256, 0, stream>>>(Qp, Kp, Vp, VT);
  ctx_kernel<<<1024, 256, 0, stream>>>(Qp, Kp, VT, CTX);

  gemm_out_kernel<<<256, 512, 0, stream>>>(CTX, Wob, bo, out);
}

// Round 11
// 222.867 us; speedup vs baseline: 1.0518x; 1.0518x over previous
//
#include <hip/hip_runtime.h>
#include <hip/hip_bf16.h>
#include <cstdint>
#include <cstddef>

typedef __bf16 bf16x8 __attribute__((ext_vector_type(8)));
typedef __bf16 bf16x4 __attribute__((ext_vector_type(4)));
typedef __bf16 bf16x2 __attribute__((ext_vector_type(2)));
typedef float  f32x4  __attribute__((ext_vector_type(4)));

static constexpr int TSEQ  = 2048;
static constexpr int DM    = 1024;
static constexpr int NH    = 16;
static constexpr int HD    = 64;
static constexpr int BATCH = 4;
// exp(s/8) = 2^(s * log2(e)/8)
static constexpr float SCL = 0.18033688011112042f;

// async global->LDS, 16B per lane; LDS dest is wave-uniform base + lane*16
__device__ __forceinline__ void gload16(const __bf16* g, __bf16* l) {
  __builtin_amdgcn_global_load_lds((const __attribute__((address_space(1))) void*)g,
                                   (__attribute__((address_space(3))) void*)l, 16, 0, 0);
}

#define PBAR()  asm volatile("s_barrier" ::: "memory")
#define LGKM()  asm volatile("s_waitcnt lgkmcnt(0)" ::: "memory")

// ---------------- fp32 -> bf16 convert ----------------
__global__ __launch_bounds__(256) void cvt_kernel(const float* __restrict__ in,
                                                  __bf16* __restrict__ out, int n4) {
  int i = blockIdx.x * 256 + threadIdx.x;
  if (i < n4) {
    float4 v = reinterpret_cast<const float4*>(in)[i];
    bf16x4 o;
    o[0] = (__bf16)v.x; o[1] = (__bf16)v.y; o[2] = (__bf16)v.z; o[3] = (__bf16)v.w;
    reinterpret_cast<bf16x4*>(out)[i] = o;
  }
}

// 4 weight matrices in one launch (blockIdx.y selects)
__global__ __launch_bounds__(256) void cvt4_kernel(
    const float* __restrict__ a, const float* __restrict__ bsrc,
    const float* __restrict__ c, const float* __restrict__ d,
    __bf16* __restrict__ oa, __bf16* __restrict__ ob,
    __bf16* __restrict__ oc, __bf16* __restrict__ od, int n4) {
  const float* src = (blockIdx.y == 0) ? a : (blockIdx.y == 1) ? bsrc
                    : (blockIdx.y == 2) ? c : d;
  __bf16* dst = (blockIdx.y == 0) ? oa : (blockIdx.y == 1) ? ob
               : (blockIdx.y == 2) ? oc : od;
  int i = blockIdx.x * 256 + threadIdx.x;
  if (i < n4) {
    float4 v = reinterpret_cast<const float4*>(src)[i];
    bf16x4 o;
    o[0] = (__bf16)v.x; o[1] = (__bf16)v.y; o[2] = (__bf16)v.z; o[3] = (__bf16)v.w;
    reinterpret_cast<bf16x4*>(dst)[i] = o;
  }
}

// ---------------- QKV GEMM body: 256x256, BK=64, 8 waves, R6 4-phase counted-vmcnt ----------------
// REVERTED to the R6/R8 JIT-read schedule (70 us, VGPR 116, no spill).
// Unified reg budget at 2 waves/SIMD = 256/wave; acc=128 AGPR leaves 128 VGPRs —
// the R9/R10 read-ahead (~160 live VGPRs) structurally cannot fit (spilled 40MB).
template <typename OUT_T>
__device__ __forceinline__ void gemm_body8(
    const __bf16* __restrict__ A, const __bf16* __restrict__ W,
    const float* __restrict__ bias, OUT_T* __restrict__ C,
    int i0, int o0, __bf16* lA, __bf16* lB) {
  const int tid = threadIdx.x;          // 0..511
  const int l = tid & 63, lr = l & 15, lg = l >> 4;
  const int w = tid >> 6;
  const int wr = w >> 2, wc = w & 3;

  f32x4 acc[8][4];
  const f32x4 fzero = {0.f, 0.f, 0.f, 0.f};
#pragma unroll
  for (int mi = 0; mi < 8; ++mi)
#pragma unroll
    for (int ni = 0; ni < 4; ++ni) acc[mi][ni] = fzero;

  const int s_row = tid >> 3;           // 0..63
  const int s_cc  = tid & 7;
  const __bf16* Ab = A + (size_t)i0 * DM;
  const __bf16* Wb = W + (size_t)o0 * DM;

  auto stage = [&](const __bf16* G, __bf16* L, int buf, int kt, int h) {
#pragma unroll
    for (int rr = 0; rr < 2; ++rr) {
      int row = h * 128 + rr * 64 + s_row;
      gload16(G + (size_t)row * DM + kt * 64 + ((s_cc ^ (row & 7)) << 3),
              L + buf * 16384 + (h * 128 + rr * 64) * 64 + tid * 8);
    }
  };
  auto rd = [&](const __bf16* base, int row, int ks) {
    int chunk = (ks * 4 + lg) ^ (row & 7);
    return *(const bf16x8*)(base + row * 64 + chunk * 8);
  };

  const int NT = DM / 64;               // 16 K-tiles

  // prologue: tiles 0 and 1 fully staged; wait tile 0 (8 newest = tile 1)
#pragma unroll
  for (int h = 0; h < 2; ++h) { stage(Ab, lA, 0, 0, h); stage(Wb, lB, 0, 0, h); }
#pragma unroll
  for (int h = 0; h < 2; ++h) { stage(Ab, lA, 1, 1, h); stage(Wb, lB, 1, 1, h); }
  asm volatile("s_waitcnt vmcnt(8)" ::: "memory");
  PBAR();

  for (int t = 0; t < NT; ++t) {
    const int cur = t & 1;
    const __bf16* cA = lA + cur * 16384;
    const __bf16* cB = lB + cur * 16384;
    const bool pre = (t + 2 < NT);

    bf16x8 afl[4][2], bfl[2][2], afh[4][2], bfh[2][2];

    // ---- phase 1: mi-lo x ni-lo ----
#pragma unroll
    for (int mi = 0; mi < 4; ++mi)
#pragma unroll
      for (int ks = 0; ks < 2; ++ks)
        afl[mi][ks] = rd(cA, wr * 64 + mi * 16 + lr, ks);
#pragma unroll
    for (int ni = 0; ni < 2; ++ni)
#pragma unroll
      for (int ks = 0; ks < 2; ++ks)
        bfl[ni][ks] = rd(cB, wc * 32 + ni * 16 + lr, ks);
    PBAR(); LGKM();
    __builtin_amdgcn_s_setprio(1);
#pragma unroll
    for (int mi = 0; mi < 4; ++mi)
#pragma unroll
      for (int ni = 0; ni < 2; ++ni)
#pragma unroll
        for (int ks = 0; ks < 2; ++ks)
          acc[mi][ni] = __builtin_amdgcn_mfma_f32_16x16x32_bf16(
              afl[mi][ks], bfl[ni][ks], acc[mi][ni], 0, 0, 0);
    __builtin_amdgcn_s_setprio(0);
    PBAR();

    // ---- phase 2: mi-lo x ni-hi; stage Bh0(t+2) ----
#pragma unroll
    for (int ni = 0; ni < 2; ++ni)
#pragma unroll
      for (int ks = 0; ks < 2; ++ks)
        bfh[ni][ks] = rd(cB, 128 + wc * 32 + ni * 16 + lr, ks);
    if (pre) stage(Wb, lB, cur, t + 2, 0);
    PBAR(); LGKM();
    __builtin_amdgcn_s_setprio(1);
#pragma unroll
    for (int mi = 0; mi < 4; ++mi)
#pragma unroll
      for (int ni = 0; ni < 2; ++ni)
#pragma unroll
        for (int ks = 0; ks < 2; ++ks)
          acc[mi][ni + 2] = __builtin_amdgcn_mfma_f32_16x16x32_bf16(
              afl[mi][ks], bfh[ni][ks], acc[mi][ni + 2], 0, 0, 0);
    __builtin_amdgcn_s_setprio(0);
    PBAR();

    // ---- phase 3: mi-hi x ni-lo (bf_lo held); stage Ah0,Bh1(t+2) ----
#pragma unroll
    for (int mi = 0; mi < 4; ++mi)
#pragma unroll
      for (int ks = 0; ks < 2; ++ks)
        afh[mi][ks] = rd(cA, 128 + wr * 64 + mi * 16 + lr, ks);
    if (pre) { stage(Ab, lA, cur, t + 2, 0); stage(Wb, lB, cur, t + 2, 1); }
    PBAR(); LGKM();
    __builtin_amdgcn_s_setprio(1);
#pragma unroll
    for (int mi = 0; mi < 4; ++mi)
#pragma unroll
      for (int ni = 0; ni < 2; ++ni)
#pragma unroll
        for (int ks = 0; ks < 2; ++ks)
          acc[mi + 4][ni] = __builtin_amdgcn_mfma_f32_16x16x32_bf16(
              afh[mi][ks], bfl[ni][ks], acc[mi + 4][ni], 0, 0, 0);
    __builtin_amdgcn_s_setprio(0);
    PBAR();

    // ---- phase 4: mi-hi x ni-hi (held regs); stage Ah1(t+2); counted vmcnt ----
    if (pre) stage(Ab, lA, cur, t + 2, 1);
    if (pre)                asm volatile("s_waitcnt vmcnt(8)" ::: "memory");
    else if (t + 1 < NT)    asm volatile("s_waitcnt vmcnt(0)" ::: "memory");
    PBAR();
    __builtin_amdgcn_s_setprio(1);
#pragma unroll
    for (int mi = 0; mi < 4; ++mi)
#pragma unroll
      for (int ni = 0; ni < 2; ++ni)
#pragma unroll
        for (int ks = 0; ks < 2; ++ks)
          acc[mi + 4][ni + 2] = __builtin_amdgcn_mfma_f32_16x16x32_bf16(
              afh[mi][ks], bfh[ni][ks], acc[mi + 4][ni + 2], 0, 0, 0);
    __builtin_amdgcn_s_setprio(0);
    PBAR();
  }

#pragma unroll
  for (int ni = 0; ni < 4; ++ni) {
    int colb = (ni < 2) ? (wc * 32 + ni * 16) : (128 + wc * 32 + (ni - 2) * 16);
    int col = o0 + colb + lr;
    float bb = bias[col];
#pragma unroll
    for (int mi = 0; mi < 8; ++mi) {
      int rowb = (mi < 4) ? (wr * 64 + mi * 16) : (128 + wr * 64 + (mi - 4) * 16);
      int row = i0 + rowb + lg * 4;
#pragma unroll
      for (int r = 0; r < 4; ++r)
        C[(size_t)(row + r) * DM + col] = (OUT_T)(acc[mi][ni][r] + bb);
    }
  }
}

// QKV fused over N=3072: grid 384 = 32 mi * 12 nig (256x256 tiles), XCD-grouped.
__global__ __launch_bounds__(512, 2) void gemm_qkv_kernel(
    const __bf16* __restrict__ A,
    const __bf16* __restrict__ W0, const __bf16* __restrict__ W1,
    const __bf16* __restrict__ W2,
    const float* __restrict__ b0, const float* __restrict__ b1,
    const float* __restrict__ b2,
    __bf16* __restrict__ O0, __bf16* __restrict__ O1, __bf16* __restrict__ O2) {
  __shared__ __align__(16) __bf16 lA[2 * 256 * 64];
  __shared__ __align__(16) __bf16 lB[2 * 256 * 64];
  const int flat = blockIdx.x;
  const int xcd = flat & 7, idx = flat >> 3;       // idx 0..47
  const int mi = xcd * 4 + idx / 12;               // 0..31
  const int nig = idx % 12;                        // 0..11
  const int z = nig >> 2;
  const int o0 = (nig & 3) * 256;
  const __bf16* W = (z == 0) ? W0 : (z == 1) ? W1 : W2;
  const float* bias = (z == 0) ? b0 : (z == 1) ? b1 : b2;
  __bf16* C = (z == 0) ? O0 : (z == 1) ? O1 : O2;
  gemm_body8<__bf16>(A, W, bias, C, mi * 256, o0, lA, lB);
}

// ---------------- out-proj GEMM: 128x256 tile, grid 256 ----------------
template <typename OUT_T>
__device__ __forceinline__ void gemm_body2(
    const __bf16* __restrict__ A, const __bf16* __restrict__ W,
    const float* __restrict__ bias, OUT_T* __restrict__ C,
    int i0, int o0, __bf16* lA, __bf16* lB) {
  const int tid = threadIdx.x;          // 0..511
  const int l = tid & 63, lr = l & 15, lg = l >> 4;
  const int w = tid >> 6;
  const int wr = w >> 2, wc = w & 3;

  f32x4 acc[4][4];
  const f32x4 fzero = {0.f, 0.f, 0.f, 0.f};
#pragma unroll
  for (int mi = 0; mi < 4; ++mi)
#pragma unroll
    for (int ni = 0; ni < 4; ++ni) acc[mi][ni] = fzero;

  const int s_row = tid >> 3;
  const int s_cc  = tid & 7;
  const int NT = DM / 64;  // 16

  {
#pragma unroll
    for (int n = 0; n < 2; ++n) {
      int row = n * 64 + s_row;
      gload16(A + (size_t)(i0 + row) * DM + ((s_cc ^ (row & 7)) << 3),
              lA + n * 4096 + tid * 8);
    }
#pragma unroll
    for (int n = 0; n < 4; ++n) {
      int row = n * 64 + s_row;
      gload16(W + (size_t)(o0 + row) * DM + ((s_cc ^ (row & 7)) << 3),
              lB + n * 4096 + tid * 8);
    }
  }
  asm volatile("s_waitcnt vmcnt(0)" ::: "memory");
  __syncthreads();

  for (int t = 0; t < NT; ++t) {
    const int cur = t & 1;
    if (t + 1 < NT) {
      const int k0 = (t + 1) * 64;
      const int nxt = cur ^ 1;
#pragma unroll
      for (int n = 0; n < 2; ++n) {
        int row = n * 64 + s_row;
        gload16(A + (size_t)(i0 + row) * DM + k0 + ((s_cc ^ (row & 7)) << 3),
                lA + nxt * 8192 + n * 4096 + tid * 8);
      }
#pragma unroll
      for (int n = 0; n < 4; ++n) {
        int row = n * 64 + s_row;
        gload16(W + (size_t)(o0 + row) * DM + k0 + ((s_cc ^ (row & 7)) << 3),
                lB + nxt * 16384 + n * 4096 + tid * 8);
      }
    }

    const __bf16* cA = lA + cur * 8192;
    const __bf16* cB = lB + cur * 16384;

    bf16x8 af[4][2], bf_[2][2];
#pragma unroll
    for (int mi = 0; mi < 4; ++mi)
#pragma unroll
      for (int ks = 0; ks < 2; ++ks) {
        int row = wr * 64 + mi * 16 + lr;
        int chunk = (ks * 4 + lg) ^ (row & 7);
        af[mi][ks] = *(const bf16x8*)(cA + row * 64 + chunk * 8);
      }
#pragma unroll
    for (int ni = 0; ni < 2; ++ni)
#pragma unroll
      for (int ks = 0; ks < 2; ++ks) {
        int row = wc * 64 + ni * 16 + lr;
        int chunk = (ks * 4 + lg) ^ (row & 7);
        bf_[ni][ks] = *(const bf16x8*)(cB + row * 64 + chunk * 8);
      }
    __builtin_amdgcn_s_setprio(1);
#pragma unroll
    for (int mi = 0; mi < 4; ++mi)
#pragma unroll
      for (int ni = 0; ni < 2; ++ni)
#pragma unroll
        for (int ks = 0; ks < 2; ++ks)
          acc[mi][ni] = __builtin_amdgcn_mfma_f32_16x16x32_bf16(
              af[mi][ks], bf_[ni][ks], acc[mi][ni], 0, 0, 0);
    __builtin_amdgcn_s_setprio(0);

#pragma unroll
    for (int ni = 0; ni < 2; ++ni)
#pragma unroll
      for (int ks = 0; ks < 2; ++ks) {
        int row = wc * 64 + (ni + 2) * 16 + lr;
        int chunk = (ks * 4 + lg) ^ (row & 7);
        bf_[ni][ks] = *(const bf16x8*)(cB + row * 64 + chunk * 8);
      }
    __builtin_amdgcn_s_setprio(1);
#pragma unroll
    for (int mi = 0; mi < 4; ++mi)
#pragma unroll
      for (int ni = 0; ni < 2; ++ni)
#pragma unroll
        for (int ks = 0; ks < 2; ++ks)
          acc[mi][ni + 2] = __builtin_amdgcn_mfma_f32_16x16x32_bf16(
              af[mi][ks], bf_[ni][ks], acc[mi][ni + 2], 0, 0, 0);
    __builtin_amdgcn_s_setprio(0);

    if (t + 1 < NT) {
      asm volatile("s_waitcnt vmcnt(0)" ::: "memory");
      __syncthreads();
    }
  }

#pragma unroll
  for (int ni = 0; ni < 4; ++ni) {
    int col = o0 + wc * 64 + ni * 16 + lr;
    float bb = bias[col];
#pragma unroll
    for (int mi = 0; mi < 4; ++mi) {
      int row = i0 + wr * 64 + mi * 16 + lg * 4;
#pragma unroll
      for (int r = 0; r < 4; ++r)
        C[(size_t)(row + r) * DM + col] = (OUT_T)(acc[mi][ni][r] + bb);
    }
  }
}

// Output GEMM: grid 256 = 64 mi * 4 ni (exactly 1 block/CU), XCD-grouped.
__global__ __launch_bounds__(512, 2) void gemm_out_kernel(
    const __bf16* __restrict__ A, const __bf16* __restrict__ W,
    const float* __restrict__ bias, float* __restrict__ C) {
  __shared__ __align__(16) __bf16 lA[2 * 128 * 64];
  __shared__ __align__(16) __bf16 lB[2 * 256 * 64];
  const int flat = blockIdx.x;
  const int xcd = flat & 7, idx = flat >> 3;       // idx 0..31
  const int mi = xcd * 8 + (idx & 7);              // 0..63
  const int ni = idx >> 3;                         // 0..3
  gemm_body2<float>(A, W, bias, C, mi * 128, ni * 256, lA, lB);
}

// ---------------- pass B: column sums c[k] = sum_{q>=k} exp(s[q,k]); VT = V^T / c ----------------
// flat grid 1024; XCD-grouped; k-tile pairing {bx, 31-bx} -> constant work.
__global__ __launch_bounds__(256) void colstats_kernel(
    const __bf16* __restrict__ Q, const __bf16* __restrict__ K,
    const __bf16* __restrict__ V, __bf16* __restrict__ VT) {
  const int flat = blockIdx.x;
  const int wid = (flat & 7) * 128 + (flat >> 3);  // 0..1023
  const int g = wid >> 4, bx = wid & 15;
  const int h = g & 15, b = g >> 4;
  const int tid = threadIdx.x;
  const int w = tid >> 6, l = tid & 63, lr = l & 15, lg = l >> 4;
  const size_t base = (size_t)b * TSEQ * DM + (size_t)h * HD;

  __shared__ float part[4][64];
  __shared__ float invc[64];

  for (int ph = 0; ph < 2; ++ph) {
    const int kt = ph ? (31 - bx) : bx;
    const int k0 = kt * 64;

    bf16x8 kf[4][2];
#pragma unroll
    for (int ct = 0; ct < 4; ++ct)
#pragma unroll
      for (int ks = 0; ks < 2; ++ks)
        kf[ct][ks] = *(const bf16x8*)(K + base + (size_t)(k0 + ct * 16 + lr) * DM +
                                      ks * 32 + lg * 8);

    float csum[4] = {0.f, 0.f, 0.f, 0.f};
    const int nchunks = (TSEQ - k0) >> 4;  // >= 4 always
    for (int jj = w; jj < nchunks; jj += 4) {
      int qrow = k0 + jj * 16;
      bf16x8 a0 = *(const bf16x8*)(Q + base + (size_t)(qrow + lr) * DM + lg * 8);
      bf16x8 a1 = *(const bf16x8*)(Q + base + (size_t)(qrow + lr) * DM + 32 + lg * 8);
      const bool interior = (jj >= 4);  // whole chunk strictly below diagonal band
#pragma unroll
      for (int ct = 0; ct < 4; ++ct) {
        f32x4 s = {0.f, 0.f, 0.f, 0.f};
        s = __builtin_amdgcn_mfma_f32_16x16x32_bf16(a0, kf[ct][0], s, 0, 0, 0);
        s = __builtin_amdgcn_mfma_f32_16x16x32_bf16(a1, kf[ct][1], s, 0, 0, 0);
        if (interior) {
#pragma unroll
          for (int r = 0; r < 4; ++r) csum[ct] += __builtin_amdgcn_exp2f(s[r] * SCL);
        } else {
#pragma unroll
          for (int r = 0; r < 4; ++r) {
            int ql = jj * 16 + lg * 4 + r;
            int kl = ct * 16 + lr;
            float e = __builtin_amdgcn_exp2f(s[r] * SCL);
            csum[ct] += (ql >= kl) ? e : 0.f;
          }
        }
      }
    }

#pragma unroll
    for (int ct = 0; ct < 4; ++ct) {
      csum[ct] += __shfl_xor(csum[ct], 16, 64);
      csum[ct] += __shfl_xor(csum[ct], 32, 64);
    }

    if (l < 16) {
#pragma unroll
      for (int ct = 0; ct < 4; ++ct) part[w][ct * 16 + l] = csum[ct];
    }
    __syncthreads();
    if (tid < 64) {
      float c = part[0][tid] + part[1][tid] + part[2][tid] + part[3][tid];
      invc[tid] = 1.0f / c;
    }
    __syncthreads();

    // VT[b,h][d][k] = V[k][d] * invc ; thread t: d = t>>2, k-cols (t&3)*16..+15
    const int d = tid >> 2, gq = tid & 3;
    size_t vtb = (((size_t)(b * NH + h)) * HD + d) * TSEQ + k0 + gq * 16;
#pragma unroll
    for (int kc = 0; kc < 16; kc += 2) {
      int kl = gq * 16 + kc;
      float v0 = (float)V[base + (size_t)(k0 + kl) * DM + d] * invc[kl];
      float v1 = (float)V[base + (size_t)(k0 + kl + 1) * DM + d] * invc[kl + 1];
      bf16x2 o; o[0] = (__bf16)v0; o[1] = (__bf16)v1;
      *(bf16x2*)(VT + vtb + kc) = o;
    }
    __syncthreads();  // part/invc reuse safety across phases
  }
}

// XOR swizzle (involution) on element index of a [64][64] bf16 tile
__device__ __forceinline__ int swz(int e) { return e ^ (((e >> 6) & 7) << 3); }

// ---------------- pass C (FUSED x4): q-tiles {31-bx, 23-bx, 8+bx, bx} in ONE K-loop ----------------
// grid 512 (2 blocks/CU, 8 waves/CU); per K-tile the K/V LDS reads feed FOUR
// tiles' MFMAs: 24 b128 + 16 b64 DS per 64 MFMA = 6 cy/MFMA vs 2-way's 9 —
// 33% less DS (the measured bottleneck). Work constant: 66 K-steps per block.
// Regs ~106 VGPR + 64 AGPR = 170 <= 256 budget at 2 waves/SIMD -> (256,2).
__global__ __launch_bounds__(256, 2) void ctx_kernel(
    const __bf16* __restrict__ Q, const __bf16* __restrict__ K,
    const __bf16* __restrict__ VT, __bf16* __restrict__ CTX) {
  __shared__ __align__(16) __bf16 lK[4096];
  __shared__ __align__(16) __bf16 lV[4096];
  __shared__ __align__(16) __bf16 lP[4][4][16 * 88];   // [wave][tile]
  const int flat = blockIdx.x;                  // 0..511
  const int wid = (flat & 7) * 64 + (flat >> 3);  // 0..511, XCD-grouped
  const int g = wid >> 3, bx = wid & 7;         // g: (b,h) 0..63
  const int h = g & 15, b = g >> 4;
  const int tid = threadIdx.x;
  const int w = tid >> 6, l = tid & 63, lr = l & 15, lg = l >> 4;
  const size_t base = (size_t)b * TSEQ * DM + (size_t)h * HD;
  const size_t vtb = ((size_t)(b * NH + h)) * HD * TSEQ;

  const int qt[4] = {31 - bx, 23 - bx, 8 + bx, bx};  // descending; sum(qt+1)=66

  const int srow = w * 8 + (l >> 3);
  const int scol = (((l & 7) ^ (l >> 3)) << 3);

  bf16x8 qf[4][2];
#pragma unroll
  for (int i = 0; i < 4; ++i)
#pragma unroll
    for (int ks = 0; ks < 2; ++ks)
      qf[i][ks] = *(const bf16x8*)(Q + base +
          (size_t)(qt[i] * 64 + w * 16 + lr) * DM + ks * 32 + lg * 8);

  f32x4 acc[4][4];
  const f32x4 fzero = {0.f, 0.f, 0.f, 0.f};
#pragma unroll
  for (int i = 0; i < 4; ++i)
#pragma unroll
    for (int dt = 0; dt < 4; ++dt) acc[i][dt] = fzero;

  for (int kt = 0; kt <= qt[0]; ++kt) {
    const int k0 = kt * 64;
    __syncthreads();   // prior iter's LDS reads done before overwrite
#pragma unroll
    for (int n = 0; n < 2; ++n) {
      gload16(K + base + (size_t)(k0 + n * 32 + srow) * DM + scol,
              lK + n * 2048 + w * 512);
      gload16(VT + vtb + (size_t)(n * 32 + srow) * TSEQ + k0 + scol,
              lV + n * 2048 + w * 512);
    }
    asm volatile("s_waitcnt vmcnt(0)" ::: "memory");
    __syncthreads();

    // QK for all active tiles, sharing kb reads
#pragma unroll
    for (int ct = 0; ct < 4; ++ct) {
      bf16x8 kb[2];
#pragma unroll
      for (int ks = 0; ks < 2; ++ks) {
        int e = (ct * 16 + lr) * 64 + ks * 32 + lg * 8;
        kb[ks] = *(const bf16x8*)(lK + swz(e));
      }
#pragma unroll
      for (int i = 0; i < 4; ++i) {
        if (kt <= qt[i]) {
          f32x4 s = {0.f, 0.f, 0.f, 0.f};
          s = __builtin_amdgcn_mfma_f32_16x16x32_bf16(kb[0], qf[i][0], s, 0, 0, 0);
          s = __builtin_amdgcn_mfma_f32_16x16x32_bf16(kb[1], qf[i][1], s, 0, 0, 0);
          bf16x4 pk;
          if (kt == qt[i]) {
#pragma unroll
            for (int r = 0; r < 4; ++r) {
              int ql = w * 16 + lr, kl = ct * 16 + lg * 4 + r;
              pk[r] = (__bf16)((ql >= kl) ? __builtin_amdgcn_exp2f(s[r] * SCL) : 0.f);
            }
          } else {
#pragma unroll
            for (int r = 0; r < 4; ++r)
              pk[r] = (__bf16)__builtin_amdgcn_exp2f(s[r] * SCL);
          }
          *(bf16x4*)(&lP[w][i][lr * 88 + ct * 16 + lg * 4]) = pk;
        }
      }
    }
    asm volatile("" ::: "memory");  // same-wave DS in-order: P writes before reads

    bf16x8 pa[4][2];
#pragma unroll
    for (int i = 0; i < 4; ++i)
      if (kt <= qt[i]) {
#pragma unroll
        for (int ks = 0; ks < 2; ++ks)
          pa[i][ks] = *(const bf16x8*)(&lP[w][i][lr * 88 + ks * 32 + lg * 8]);
      }
#pragma unroll
    for (int dt = 0; dt < 4; ++dt) {
#pragma unroll
      for (int ks = 0; ks < 2; ++ks) {
        int e = (dt * 16 + lr) * 64 + ks * 32 + lg * 8;
        bf16x8 vb8 = *(const bf16x8*)(lV + swz(e));   // shared by all 4 tiles
#pragma unroll
        for (int i = 0; i < 4; ++i)
          if (kt <= qt[i])
            acc[i][dt] = __builtin_amdgcn_mfma_f32_16x16x32_bf16(
                pa[i][ks], vb8, acc[i][dt], 0, 0, 0);
      }
    }
  }

#pragma unroll
  for (int i = 0; i < 4; ++i)
#pragma unroll
    for (int dt = 0; dt < 4; ++dt)
#pragma unroll
      for (int r = 0; r < 4; ++r)
        CTX[base + (size_t)(qt[i] * 64 + w * 16 + lg * 4 + r) * DM + dt * 16 + lr] =
            (__bf16)acc[i][dt][r];
}

extern "C" void kernel_launch(void* const* d_in, const int* in_sizes, int n_in,
                              void* d_out, int out_size, void* d_ws, size_t ws_size,
                              hipStream_t stream) {
  const float* q  = (const float*)d_in[0];
  const float* Wq = (const float*)d_in[3];
  const float* bq = (const float*)d_in[4];
  const float* Wk = (const float*)d_in[5];
  const float* bk = (const float*)d_in[6];
  const float* Wv = (const float*)d_in[7];
  const float* bv = (const float*)d_in[8];
  const float* Wo = (const float*)d_in[9];
  const float* bo = (const float*)d_in[10];
  float* out = (float*)d_out;

  const size_t NTOK = (size_t)BATCH * TSEQ;  // 8192
  char* ws = (char*)d_ws;
  __bf16* qb  = (__bf16*)ws; ws += NTOK * DM * 2;   // reused as CTX after QKV GEMMs
  __bf16* Wqb = (__bf16*)ws; ws += (size_t)DM * DM * 2;
  __bf16* Wkb = (__bf16*)ws; ws += (size_t)DM * DM * 2;
  __bf16* Wvb = (__bf16*)ws; ws += (size_t)DM * DM * 2;
  __bf16* Wob = (__bf16*)ws; ws += (size_t)DM * DM * 2;
  __bf16* Qp  = (__bf16*)ws; ws += NTOK * DM * 2;
  __bf16* Kp  = (__bf16*)ws; ws += NTOK * DM * 2;
  __bf16* Vp  = (__bf16*)ws; ws += NTOK * DM * 2;
  __bf16* VT  = (__bf16*)ws; ws += (size_t)BATCH * NH * HD * TSEQ * 2;
  __bf16* CTX = qb;  // qb dead after the QKV GEMMs

  const int nq4 = (int)(NTOK * DM / 4);
  const int nw4 = DM * DM / 4;
  cvt_kernel<<<(nq4 + 255) / 256, 256, 0, stream>>>(q, qb, nq4);
  cvt4_kernel<<<dim3((nw4 + 255) / 256, 4), 256, 0, stream>>>(
      Wq, Wk, Wv, Wo, Wqb, Wkb, Wvb, Wob, nw4);

  gemm_qkv_kernel<<<384, 512, 0, stream>>>(qb, Wqb, Wkb, Wvb, bq, bk, bv,
                                           Qp, Kp, Vp);

  colstats_kernel<<<1024, 256, 0, stream>>>(Qp, Kp, Vp, VT);
  ctx_kernel<<<512, 256, 0, stream>>>(Qp, Kp, VT, CTX);

  gemm_out_kernel<<<256, 512, 0, stream>>>(CTX, Wob, bo, out);
}

// Round 12
// 209.076 us; speedup vs baseline: 1.1212x; 1.0660x over previous
//
#include <hip/hip_runtime.h>
#include <hip/hip_bf16.h>
#include <cstdint>
#include <cstddef>

typedef __bf16 bf16x8 __attribute__((ext_vector_type(8)));
typedef __bf16 bf16x4 __attribute__((ext_vector_type(4)));
typedef __bf16 bf16x2 __attribute__((ext_vector_type(2)));
typedef float  f32x4  __attribute__((ext_vector_type(4)));

static constexpr int TSEQ  = 2048;
static constexpr int DM    = 1024;
static constexpr int NH    = 16;
static constexpr int HD    = 64;
static constexpr int BATCH = 4;
// exp(s/8) = 2^(s * log2(e)/8)
static constexpr float SCL = 0.18033688011112042f;

// async global->LDS, 16B per lane; LDS dest is wave-uniform base + lane*16
__device__ __forceinline__ void gload16(const __bf16* g, __bf16* l) {
  __builtin_amdgcn_global_load_lds((const __attribute__((address_space(1))) void*)g,
                                   (__attribute__((address_space(3))) void*)l, 16, 0, 0);
}

#define PBAR()  asm volatile("s_barrier" ::: "memory")
#define LGKM()  asm volatile("s_waitcnt lgkmcnt(0)" ::: "memory")

// ---------------- fp32 -> bf16 convert ----------------
__global__ __launch_bounds__(256) void cvt_kernel(const float* __restrict__ in,
                                                  __bf16* __restrict__ out, int n4) {
  int i = blockIdx.x * 256 + threadIdx.x;
  if (i < n4) {
    float4 v = reinterpret_cast<const float4*>(in)[i];
    bf16x4 o;
    o[0] = (__bf16)v.x; o[1] = (__bf16)v.y; o[2] = (__bf16)v.z; o[3] = (__bf16)v.w;
    reinterpret_cast<bf16x4*>(out)[i] = o;
  }
}

// 4 weight matrices in one launch (blockIdx.y selects)
__global__ __launch_bounds__(256) void cvt4_kernel(
    const float* __restrict__ a, const float* __restrict__ bsrc,
    const float* __restrict__ c, const float* __restrict__ d,
    __bf16* __restrict__ oa, __bf16* __restrict__ ob,
    __bf16* __restrict__ oc, __bf16* __restrict__ od, int n4) {
  const float* src = (blockIdx.y == 0) ? a : (blockIdx.y == 1) ? bsrc
                    : (blockIdx.y == 2) ? c : d;
  __bf16* dst = (blockIdx.y == 0) ? oa : (blockIdx.y == 1) ? ob
               : (blockIdx.y == 2) ? oc : od;
  int i = blockIdx.x * 256 + threadIdx.x;
  if (i < n4) {
    float4 v = reinterpret_cast<const float4*>(src)[i];
    bf16x4 o;
    o[0] = (__bf16)v.x; o[1] = (__bf16)v.y; o[2] = (__bf16)v.z; o[3] = (__bf16)v.w;
    reinterpret_cast<bf16x4*>(dst)[i] = o;
  }
}

// ---------------- QKV GEMM: 256x192 tile, BK=64, 8 waves, R6 4-phase counted-vmcnt ----------------
// N=3072 (contiguous Wqkv [3][1024][1024]) in 192-wide tiles -> grid 512 =
// EXACTLY 2 full CU rounds (the 256-wide version's 384 blocks = 1.5 rounds
// idled half the chip for round 2, a structural 25% loss). Per-wave 128x48:
// acc 96 AGPR + ~115 VGPR = 211 <= 256/wave budget at 2 waves/SIMD.
// Outputs to contiguous QKVp [3][8192][1024]; 16-col write groups never cross
// a 1024 boundary so z-select is uniform per group.
__global__ __launch_bounds__(512, 2) void gemm_qkv_kernel(
    const __bf16* __restrict__ A, const __bf16* __restrict__ Wqkv,
    const float* __restrict__ b0, const float* __restrict__ b1,
    const float* __restrict__ b2, __bf16* __restrict__ QKVp) {
  __shared__ __align__(16) __bf16 lA[2 * 256 * 64];   // 64 KB
  __shared__ __align__(16) __bf16 lB[2 * 192 * 64];   // 48 KB
  const int flat = blockIdx.x;                 // 0..511
  const int xcd = flat & 7, idx = flat >> 3;   // idx 0..63
  const int mi = xcd * 4 + (idx & 3);          // 0..31 (A-panels grouped per XCD)
  const int nig = idx >> 2;                    // 0..15
  const int i0 = mi * 256, o0 = nig * 192;

  const int tid = threadIdx.x;
  const int l = tid & 63, lr = l & 15, lg = l >> 4;
  const int w = tid >> 6;
  const int wr = w >> 2, wc = w & 3;           // wave: rows wr*128, cols wc*48

  f32x4 acc[8][3];
  const f32x4 fzero = {0.f, 0.f, 0.f, 0.f};
#pragma unroll
  for (int mm = 0; mm < 8; ++mm)
#pragma unroll
    for (int ni = 0; ni < 3; ++ni) acc[mm][ni] = fzero;

  const int s_row = tid >> 3;                  // 0..63
  const int s_cc  = tid & 7;
  const __bf16* Ab = A + (size_t)i0 * DM;
  const __bf16* Wb = Wqkv + (size_t)o0 * DM;

  auto stageA = [&](int buf, int kt, int h) {
#pragma unroll
    for (int rr = 0; rr < 2; ++rr) {
      int row = h * 128 + rr * 64 + s_row;
      gload16(Ab + (size_t)row * DM + kt * 64 + ((s_cc ^ (row & 7)) << 3),
              lA + buf * 16384 + (h * 128 + rr * 64) * 64 + tid * 8);
    }
  };
  auto stageB = [&](int buf, int kt, int n) {
    int row = n * 64 + s_row;
    gload16(Wb + (size_t)row * DM + kt * 64 + ((s_cc ^ (row & 7)) << 3),
            lB + buf * 12288 + n * 4096 + tid * 8);
  };
  auto rdA = [&](const __bf16* base, int row, int ks) {
    int chunk = (ks * 4 + lg) ^ (row & 7);
    return *(const bf16x8*)(base + row * 64 + chunk * 8);
  };

  const int NT = DM / 64;                      // 16 K-tiles

  // prologue: tiles 0,1 fully staged (7 gloads each); vmcnt(7) -> tile 0 ready
#pragma unroll
  for (int h = 0; h < 2; ++h) stageA(0, 0, h);
#pragma unroll
  for (int n = 0; n < 3; ++n) stageB(0, 0, n);
#pragma unroll
  for (int h = 0; h < 2; ++h) stageA(1, 1, h);
#pragma unroll
  for (int n = 0; n < 3; ++n) stageB(1, 1, n);
  asm volatile("s_waitcnt vmcnt(7)" ::: "memory");
  PBAR();

  for (int t = 0; t < NT; ++t) {
    const int cur = t & 1;
    const __bf16* cA = lA + cur * 16384;
    const __bf16* cB = lB + cur * 12288;
    const bool pre = (t + 2 < NT);

    bf16x8 afl[4][2], afh[4][2], bfl[2][2], bfh[1][2];

    // ---- phase 1: Q1 = mi0-3 x ni0-1 (16 MFMA) ----
#pragma unroll
    for (int mm = 0; mm < 4; ++mm)
#pragma unroll
      for (int ks = 0; ks < 2; ++ks)
        afl[mm][ks] = rdA(cA, wr * 128 + mm * 16 + lr, ks);
#pragma unroll
    for (int ni = 0; ni < 2; ++ni)
#pragma unroll
      for (int ks = 0; ks < 2; ++ks)
        bfl[ni][ks] = rdA(cB, wc * 48 + ni * 16 + lr, ks);
    PBAR(); LGKM();
    __builtin_amdgcn_s_setprio(1);
#pragma unroll
    for (int mm = 0; mm < 4; ++mm)
#pragma unroll
      for (int ni = 0; ni < 2; ++ni)
#pragma unroll
        for (int ks = 0; ks < 2; ++ks)
          acc[mm][ni] = __builtin_amdgcn_mfma_f32_16x16x32_bf16(
              afl[mm][ks], bfl[ni][ks], acc[mm][ni], 0, 0, 0);
    __builtin_amdgcn_s_setprio(0);
    PBAR();

    // ---- phase 2: Q2 = mi0-3 x ni2 (8 MFMA); stage B n0,n1 (t+2) ----
#pragma unroll
    for (int ks = 0; ks < 2; ++ks)
      bfh[0][ks] = rdA(cB, wc * 48 + 2 * 16 + lr, ks);
    if (pre) { stageB(cur, t + 2, 0); stageB(cur, t + 2, 1); }
    PBAR(); LGKM();
    __builtin_amdgcn_s_setprio(1);
#pragma unroll
    for (int mm = 0; mm < 4; ++mm)
#pragma unroll
      for (int ks = 0; ks < 2; ++ks)
        acc[mm][2] = __builtin_amdgcn_mfma_f32_16x16x32_bf16(
            afl[mm][ks], bfh[0][ks], acc[mm][2], 0, 0, 0);
    __builtin_amdgcn_s_setprio(0);
    PBAR();

    // ---- phase 3: Q3 = mi4-7 x ni0-1 (16 MFMA); stage B n2 + A h0 (t+2) ----
#pragma unroll
    for (int mm = 0; mm < 4; ++mm)
#pragma unroll
      for (int ks = 0; ks < 2; ++ks)
        afh[mm][ks] = rdA(cA, wr * 128 + (mm + 4) * 16 + lr, ks);
    if (pre) { stageB(cur, t + 2, 2); stageA(cur, t + 2, 0); }
    PBAR(); LGKM();
    __builtin_amdgcn_s_setprio(1);
#pragma unroll
    for (int mm = 0; mm < 4; ++mm)
#pragma unroll
      for (int ni = 0; ni < 2; ++ni)
#pragma unroll
        for (int ks = 0; ks < 2; ++ks)
          acc[mm + 4][ni] = __builtin_amdgcn_mfma_f32_16x16x32_bf16(
              afh[mm][ks], bfl[ni][ks], acc[mm + 4][ni], 0, 0, 0);
    __builtin_amdgcn_s_setprio(0);
    PBAR();

    // ---- phase 4: Q4 = mi4-7 x ni2 (8 MFMA); stage A h1 (t+2); counted vmcnt ----
    if (pre) stageA(cur, t + 2, 1);
    if (pre)                asm volatile("s_waitcnt vmcnt(7)" ::: "memory");
    else if (t + 1 < NT)    asm volatile("s_waitcnt vmcnt(0)" ::: "memory");
    PBAR();
    __builtin_amdgcn_s_setprio(1);
#pragma unroll
    for (int mm = 0; mm < 4; ++mm)
#pragma unroll
      for (int ks = 0; ks < 2; ++ks)
        acc[mm + 4][2] = __builtin_amdgcn_mfma_f32_16x16x32_bf16(
            afh[mm][ks], bfh[0][ks], acc[mm + 4][2], 0, 0, 0);
    __builtin_amdgcn_s_setprio(0);
    PBAR();
  }

#pragma unroll
  for (int ni = 0; ni < 3; ++ni) {
    int col = o0 + wc * 48 + ni * 16 + lr;     // global col in [0,3072)
    int z = col >> 10, cin = col & 1023;       // uniform z per 16-col group
    const float* bp = (z == 0) ? b0 : (z == 1) ? b1 : b2;
    float bb = bp[cin];
    __bf16* O = QKVp + (size_t)z * 8192 * DM;
#pragma unroll
    for (int mm = 0; mm < 8; ++mm) {
      int row = i0 + wr * 128 + mm * 16 + lg * 4;
#pragma unroll
      for (int r = 0; r < 4; ++r)
        O[(size_t)(row + r) * DM + cin] = (__bf16)(acc[mm][ni][r] + bb);
    }
  }
}

// ---------------- out-proj GEMM: 128x256 tile, grid 256 ----------------
template <typename OUT_T>
__device__ __forceinline__ void gemm_body2(
    const __bf16* __restrict__ A, const __bf16* __restrict__ W,
    const float* __restrict__ bias, OUT_T* __restrict__ C,
    int i0, int o0, __bf16* lA, __bf16* lB) {
  const int tid = threadIdx.x;          // 0..511
  const int l = tid & 63, lr = l & 15, lg = l >> 4;
  const int w = tid >> 6;
  const int wr = w >> 2, wc = w & 3;

  f32x4 acc[4][4];
  const f32x4 fzero = {0.f, 0.f, 0.f, 0.f};
#pragma unroll
  for (int mi = 0; mi < 4; ++mi)
#pragma unroll
    for (int ni = 0; ni < 4; ++ni) acc[mi][ni] = fzero;

  const int s_row = tid >> 3;
  const int s_cc  = tid & 7;
  const int NT = DM / 64;  // 16

  {
#pragma unroll
    for (int n = 0; n < 2; ++n) {
      int row = n * 64 + s_row;
      gload16(A + (size_t)(i0 + row) * DM + ((s_cc ^ (row & 7)) << 3),
              lA + n * 4096 + tid * 8);
    }
#pragma unroll
    for (int n = 0; n < 4; ++n) {
      int row = n * 64 + s_row;
      gload16(W + (size_t)(o0 + row) * DM + ((s_cc ^ (row & 7)) << 3),
              lB + n * 4096 + tid * 8);
    }
  }
  asm volatile("s_waitcnt vmcnt(0)" ::: "memory");
  __syncthreads();

  for (int t = 0; t < NT; ++t) {
    const int cur = t & 1;
    if (t + 1 < NT) {
      const int k0 = (t + 1) * 64;
      const int nxt = cur ^ 1;
#pragma unroll
      for (int n = 0; n < 2; ++n) {
        int row = n * 64 + s_row;
        gload16(A + (size_t)(i0 + row) * DM + k0 + ((s_cc ^ (row & 7)) << 3),
                lA + nxt * 8192 + n * 4096 + tid * 8);
      }
#pragma unroll
      for (int n = 0; n < 4; ++n) {
        int row = n * 64 + s_row;
        gload16(W + (size_t)(o0 + row) * DM + k0 + ((s_cc ^ (row & 7)) << 3),
                lB + nxt * 16384 + n * 4096 + tid * 8);
      }
    }

    const __bf16* cA = lA + cur * 8192;
    const __bf16* cB = lB + cur * 16384;

    bf16x8 af[4][2], bf_[2][2];
#pragma unroll
    for (int mi = 0; mi < 4; ++mi)
#pragma unroll
      for (int ks = 0; ks < 2; ++ks) {
        int row = wr * 64 + mi * 16 + lr;
        int chunk = (ks * 4 + lg) ^ (row & 7);
        af[mi][ks] = *(const bf16x8*)(cA + row * 64 + chunk * 8);
      }
#pragma unroll
    for (int ni = 0; ni < 2; ++ni)
#pragma unroll
      for (int ks = 0; ks < 2; ++ks) {
        int row = wc * 64 + ni * 16 + lr;
        int chunk = (ks * 4 + lg) ^ (row & 7);
        bf_[ni][ks] = *(const bf16x8*)(cB + row * 64 + chunk * 8);
      }
    __builtin_amdgcn_s_setprio(1);
#pragma unroll
    for (int mi = 0; mi < 4; ++mi)
#pragma unroll
      for (int ni = 0; ni < 2; ++ni)
#pragma unroll
        for (int ks = 0; ks < 2; ++ks)
          acc[mi][ni] = __builtin_amdgcn_mfma_f32_16x16x32_bf16(
              af[mi][ks], bf_[ni][ks], acc[mi][ni], 0, 0, 0);
    __builtin_amdgcn_s_setprio(0);

#pragma unroll
    for (int ni = 0; ni < 2; ++ni)
#pragma unroll
      for (int ks = 0; ks < 2; ++ks) {
        int row = wc * 64 + (ni + 2) * 16 + lr;
        int chunk = (ks * 4 + lg) ^ (row & 7);
        bf_[ni][ks] = *(const bf16x8*)(cB + row * 64 + chunk * 8);
      }
    __builtin_amdgcn_s_setprio(1);
#pragma unroll
    for (int mi = 0; mi < 4; ++mi)
#pragma unroll
      for (int ni = 0; ni < 2; ++ni)
#pragma unroll
        for (int ks = 0; ks < 2; ++ks)
          acc[mi][ni + 2] = __builtin_amdgcn_mfma_f32_16x16x32_bf16(
              af[mi][ks], bf_[ni][ks], acc[mi][ni + 2], 0, 0, 0);
    __builtin_amdgcn_s_setprio(0);

    if (t + 1 < NT) {
      asm volatile("s_waitcnt vmcnt(0)" ::: "memory");
      __syncthreads();
    }
  }

#pragma unroll
  for (int ni = 0; ni < 4; ++ni) {
    int col = o0 + wc * 64 + ni * 16 + lr;
    float bb = bias[col];
#pragma unroll
    for (int mi = 0; mi < 4; ++mi) {
      int row = i0 + wr * 64 + mi * 16 + lg * 4;
#pragma unroll
      for (int r = 0; r < 4; ++r)
        C[(size_t)(row + r) * DM + col] = (OUT_T)(acc[mi][ni][r] + bb);
    }
  }
}

// Output GEMM: grid 256 = 64 mi * 4 ni (exactly 1 block/CU), XCD-grouped.
__global__ __launch_bounds__(512, 2) void gemm_out_kernel(
    const __bf16* __restrict__ A, const __bf16* __restrict__ W,
    const float* __restrict__ bias, float* __restrict__ C) {
  __shared__ __align__(16) __bf16 lA[2 * 128 * 64];
  __shared__ __align__(16) __bf16 lB[2 * 256 * 64];
  const int flat = blockIdx.x;
  const int xcd = flat & 7, idx = flat >> 3;       // idx 0..31
  const int mi = xcd * 8 + (idx & 7);              // 0..63
  const int ni = idx >> 3;                         // 0..3
  gemm_body2<float>(A, W, bias, C, mi * 128, ni * 256, lA, lB);
}

// ---------------- pass B: column sums c[k] = sum_{q>=k} exp(s[q,k]); VT = V^T / c ----------------
// flat grid 1024; XCD-grouped; k-tile pairing {bx, 31-bx} -> constant work.
__global__ __launch_bounds__(256) void colstats_kernel(
    const __bf16* __restrict__ Q, const __bf16* __restrict__ K,
    const __bf16* __restrict__ V, __bf16* __restrict__ VT) {
  const int flat = blockIdx.x;
  const int wid = (flat & 7) * 128 + (flat >> 3);  // 0..1023
  const int g = wid >> 4, bx = wid & 15;
  const int h = g & 15, b = g >> 4;
  const int tid = threadIdx.x;
  const int w = tid >> 6, l = tid & 63, lr = l & 15, lg = l >> 4;
  const size_t base = (size_t)b * TSEQ * DM + (size_t)h * HD;

  __shared__ float part[4][64];
  __shared__ float invc[64];

  for (int ph = 0; ph < 2; ++ph) {
    const int kt = ph ? (31 - bx) : bx;
    const int k0 = kt * 64;

    bf16x8 kf[4][2];
#pragma unroll
    for (int ct = 0; ct < 4; ++ct)
#pragma unroll
      for (int ks = 0; ks < 2; ++ks)
        kf[ct][ks] = *(const bf16x8*)(K + base + (size_t)(k0 + ct * 16 + lr) * DM +
                                      ks * 32 + lg * 8);

    float csum[4] = {0.f, 0.f, 0.f, 0.f};
    const int nchunks = (TSEQ - k0) >> 4;  // >= 4 always
    for (int jj = w; jj < nchunks; jj += 4) {
      int qrow = k0 + jj * 16;
      bf16x8 a0 = *(const bf16x8*)(Q + base + (size_t)(qrow + lr) * DM + lg * 8);
      bf16x8 a1 = *(const bf16x8*)(Q + base + (size_t)(qrow + lr) * DM + 32 + lg * 8);
      const bool interior = (jj >= 4);  // whole chunk strictly below diagonal band
#pragma unroll
      for (int ct = 0; ct < 4; ++ct) {
        f32x4 s = {0.f, 0.f, 0.f, 0.f};
        s = __builtin_amdgcn_mfma_f32_16x16x32_bf16(a0, kf[ct][0], s, 0, 0, 0);
        s = __builtin_amdgcn_mfma_f32_16x16x32_bf16(a1, kf[ct][1], s, 0, 0, 0);
        if (interior) {
#pragma unroll
          for (int r = 0; r < 4; ++r) csum[ct] += __builtin_amdgcn_exp2f(s[r] * SCL);
        } else {
#pragma unroll
          for (int r = 0; r < 4; ++r) {
            int ql = jj * 16 + lg * 4 + r;
            int kl = ct * 16 + lr;
            float e = __builtin_amdgcn_exp2f(s[r] * SCL);
            csum[ct] += (ql >= kl) ? e : 0.f;
          }
        }
      }
    }

#pragma unroll
    for (int ct = 0; ct < 4; ++ct) {
      csum[ct] += __shfl_xor(csum[ct], 16, 64);
      csum[ct] += __shfl_xor(csum[ct], 32, 64);
    }

    if (l < 16) {
#pragma unroll
      for (int ct = 0; ct < 4; ++ct) part[w][ct * 16 + l] = csum[ct];
    }
    __syncthreads();
    if (tid < 64) {
      float c = part[0][tid] + part[1][tid] + part[2][tid] + part[3][tid];
      invc[tid] = 1.0f / c;
    }
    __syncthreads();

    // VT[b,h][d][k] = V[k][d] * invc ; thread t: d = t>>2, k-cols (t&3)*16..+15
    const int d = tid >> 2, gq = tid & 3;
    size_t vtb = (((size_t)(b * NH + h)) * HD + d) * TSEQ + k0 + gq * 16;
#pragma unroll
    for (int kc = 0; kc < 16; kc += 2) {
      int kl = gq * 16 + kc;
      float v0 = (float)V[base + (size_t)(k0 + kl) * DM + d] * invc[kl];
      float v1 = (float)V[base + (size_t)(k0 + kl + 1) * DM + d] * invc[kl + 1];
      bf16x2 o; o[0] = (__bf16)v0; o[1] = (__bf16)v1;
      *(bf16x2*)(VT + vtb + kc) = o;
    }
    __syncthreads();  // part/invc reuse safety across phases
  }
}

// XOR swizzle (involution) on element index of a [64][64] bf16 tile
__device__ __forceinline__ int swz(int e) { return e ^ (((e >> 6) & 7) << 3); }

// ---------------- pass C (FUSED x2, R8 version): q-tiles {31-bx, bx} in ONE K-loop ----------------
// Single-buffered (TLP covers latency: 39KB LDS -> 4 blocks/CU = 16 waves).
// Per staged K-tile: kb8/vb8 read ONCE, feed both tiles' MFMAs.
__global__ __launch_bounds__(256, 4) void ctx_kernel(
    const __bf16* __restrict__ Q, const __bf16* __restrict__ K,
    const __bf16* __restrict__ VT, __bf16* __restrict__ CTX) {
  __shared__ __align__(16) __bf16 lK[4096];
  __shared__ __align__(16) __bf16 lV[4096];
  __shared__ __align__(16) __bf16 lP[8][16 * 88];   // [wave + 4*tile]
  const int flat = blockIdx.x;
  const int wid = (flat & 7) * 128 + (flat >> 3);  // 0..1023
  const int g = wid >> 4, bx = wid & 15;
  const int h = g & 15, b = g >> 4;
  const int tid = threadIdx.x;
  const int w = tid >> 6, l = tid & 63, lr = l & 15, lg = l >> 4;
  const size_t base = (size_t)b * TSEQ * DM + (size_t)h * HD;
  const size_t vtb = ((size_t)(b * NH + h)) * HD * TSEQ;
  __bf16* pw1 = &lP[w][0];
  __bf16* pw2 = &lP[w + 4][0];

  const int qt1 = 31 - bx, qt2 = bx;   // qt1 >= 16 > qt2 always
  const int q01 = qt1 * 64, q02 = qt2 * 64;

  const int srow = w * 8 + (l >> 3);
  const int scol = (((l & 7) ^ (l >> 3)) << 3);

  bf16x8 qf1[2], qf2[2];
#pragma unroll
  for (int ks = 0; ks < 2; ++ks) {
    qf1[ks] = *(const bf16x8*)(Q + base + (size_t)(q01 + w * 16 + lr) * DM + ks * 32 + lg * 8);
    qf2[ks] = *(const bf16x8*)(Q + base + (size_t)(q02 + w * 16 + lr) * DM + ks * 32 + lg * 8);
  }

  f32x4 acc1[4], acc2[4];
  const f32x4 fzero = {0.f, 0.f, 0.f, 0.f};
#pragma unroll
  for (int dt = 0; dt < 4; ++dt) { acc1[dt] = fzero; acc2[dt] = fzero; }

  for (int kt = 0; kt <= qt1; ++kt) {
    const int k0 = kt * 64;
    const bool two = (kt <= qt2);
    __syncthreads();   // prior iter's LDS reads done before overwrite
#pragma unroll
    for (int n = 0; n < 2; ++n) {
      gload16(K + base + (size_t)(k0 + n * 32 + srow) * DM + scol,
              lK + n * 2048 + w * 512);
      gload16(VT + vtb + (size_t)(n * 32 + srow) * TSEQ + k0 + scol,
              lV + n * 2048 + w * 512);
    }
    asm volatile("s_waitcnt vmcnt(0)" ::: "memory");
    __syncthreads();

    const bool diag1 = (kt == qt1), diag2 = (kt == qt2);
#pragma unroll
    for (int ct = 0; ct < 4; ++ct) {
      bf16x8 kb[2];
#pragma unroll
      for (int ks = 0; ks < 2; ++ks) {
        int e = (ct * 16 + lr) * 64 + ks * 32 + lg * 8;
        kb[ks] = *(const bf16x8*)(lK + swz(e));
      }
      {
        f32x4 s = {0.f, 0.f, 0.f, 0.f};
        s = __builtin_amdgcn_mfma_f32_16x16x32_bf16(kb[0], qf1[0], s, 0, 0, 0);
        s = __builtin_amdgcn_mfma_f32_16x16x32_bf16(kb[1], qf1[1], s, 0, 0, 0);
        bf16x4 pk;
        if (diag1) {
#pragma unroll
          for (int r = 0; r < 4; ++r) {
            int ql = w * 16 + lr, kl = ct * 16 + lg * 4 + r;
            pk[r] = (__bf16)((ql >= kl) ? __builtin_amdgcn_exp2f(s[r] * SCL) : 0.f);
          }
        } else {
#pragma unroll
          for (int r = 0; r < 4; ++r)
            pk[r] = (__bf16)__builtin_amdgcn_exp2f(s[r] * SCL);
        }
        *(bf16x4*)(pw1 + lr * 88 + ct * 16 + lg * 4) = pk;
      }
      if (two) {
        f32x4 s = {0.f, 0.f, 0.f, 0.f};
        s = __builtin_amdgcn_mfma_f32_16x16x32_bf16(kb[0], qf2[0], s, 0, 0, 0);
        s = __builtin_amdgcn_mfma_f32_16x16x32_bf16(kb[1], qf2[1], s, 0, 0, 0);
        bf16x4 pk;
        if (diag2) {
#pragma unroll
          for (int r = 0; r < 4; ++r) {
            int ql = w * 16 + lr, kl = ct * 16 + lg * 4 + r;
            pk[r] = (__bf16)((ql >= kl) ? __builtin_amdgcn_exp2f(s[r] * SCL) : 0.f);
          }
        } else {
#pragma unroll
          for (int r = 0; r < 4; ++r)
            pk[r] = (__bf16)__builtin_amdgcn_exp2f(s[r] * SCL);
        }
        *(bf16x4*)(pw2 + lr * 88 + ct * 16 + lg * 4) = pk;
      }
    }
    asm volatile("" ::: "memory");  // same-wave DS in-order: P writes before reads

    bf16x8 pa1[2], pa2[2];
#pragma unroll
    for (int ks = 0; ks < 2; ++ks)
      pa1[ks] = *(const bf16x8*)(pw1 + lr * 88 + ks * 32 + lg * 8);
    if (two) {
#pragma unroll
      for (int ks = 0; ks < 2; ++ks)
        pa2[ks] = *(const bf16x8*)(pw2 + lr * 88 + ks * 32 + lg * 8);
    }
#pragma unroll
    for (int dt = 0; dt < 4; ++dt) {
#pragma unroll
      for (int ks = 0; ks < 2; ++ks) {
        int e = (dt * 16 + lr) * 64 + ks * 32 + lg * 8;
        bf16x8 vb8 = *(const bf16x8*)(lV + swz(e));   // shared by both tiles
        acc1[dt] = __builtin_amdgcn_mfma_f32_16x16x32_bf16(pa1[ks], vb8, acc1[dt], 0, 0, 0);
        if (two)
          acc2[dt] = __builtin_amdgcn_mfma_f32_16x16x32_bf16(pa2[ks], vb8, acc2[dt], 0, 0, 0);
      }
    }
  }

#pragma unroll
  for (int dt = 0; dt < 4; ++dt)
#pragma unroll
    for (int r = 0; r < 4; ++r) {
      CTX[base + (size_t)(q01 + w * 16 + lg * 4 + r) * DM + dt * 16 + lr] = (__bf16)acc1[dt][r];
      CTX[base + (size_t)(q02 + w * 16 + lg * 4 + r) * DM + dt * 16 + lr] = (__bf16)acc2[dt][r];
    }
}

extern "C" void kernel_launch(void* const* d_in, const int* in_sizes, int n_in,
                              void* d_out, int out_size, void* d_ws, size_t ws_size,
                              hipStream_t stream) {
  const float* q  = (const float*)d_in[0];
  const float* Wq = (const float*)d_in[3];
  const float* bq = (const float*)d_in[4];
  const float* Wk = (const float*)d_in[5];
  const float* bk = (const float*)d_in[6];
  const float* Wv = (const float*)d_in[7];
  const float* bv = (const float*)d_in[8];
  const float* Wo = (const float*)d_in[9];
  const float* bo = (const float*)d_in[10];
  float* out = (float*)d_out;

  const size_t NTOK = (size_t)BATCH * TSEQ;  // 8192
  char* ws = (char*)d_ws;
  __bf16* qb   = (__bf16*)ws; ws += NTOK * DM * 2;      // reused as CTX later
  __bf16* Wqkv = (__bf16*)ws; ws += 3 * (size_t)DM * DM * 2;  // contiguous [3][1024][1024]
  __bf16* Wob  = (__bf16*)ws; ws += (size_t)DM * DM * 2;
  __bf16* QKVp = (__bf16*)ws; ws += 3 * NTOK * DM * 2;  // contiguous [3][8192][1024]
  __bf16* VT   = (__bf16*)ws; ws += (size_t)BATCH * NH * HD * TSEQ * 2;
  __bf16* CTX = qb;  // qb dead after the QKV GEMM

  __bf16* Qp = QKVp;
  __bf16* Kp = QKVp + NTOK * DM;
  __bf16* Vp = QKVp + 2 * NTOK * DM;

  const int nq4 = (int)(NTOK * DM / 4);
  const int nw4 = DM * DM / 4;
  cvt_kernel<<<(nq4 + 255) / 256, 256, 0, stream>>>(q, qb, nq4);
  cvt4_kernel<<<dim3((nw4 + 255) / 256, 4), 256, 0, stream>>>(
      Wq, Wk, Wv, Wo, Wqkv, Wqkv + (size_t)DM * DM, Wqkv + 2 * (size_t)DM * DM, Wob, nw4);

  gemm_qkv_kernel<<<512, 512, 0, stream>>>(qb, Wqkv, bq, bk, bv, QKVp);

  colstats_kernel<<<1024, 256, 0, stream>>>(Qp, Kp, Vp, VT);
  ctx_kernel<<<1024, 256, 0, stream>>>(Qp, Kp, VT, CTX);

  gemm_out_kernel<<<256, 512, 0, stream>>>(CTX, Wob, bo, out);
}

// Round 13
// 208.998 us; speedup vs baseline: 1.1216x; 1.0004x over previous
//
#include <hip/hip_runtime.h>
#include <hip/hip_bf16.h>
#include <cstdint>
#include <cstddef>

typedef __bf16 bf16x8 __attribute__((ext_vector_type(8)));
typedef __bf16 bf16x4 __attribute__((ext_vector_type(4)));
typedef __bf16 bf16x2 __attribute__((ext_vector_type(2)));
typedef float  f32x4  __attribute__((ext_vector_type(4)));

static constexpr int TSEQ  = 2048;
static constexpr int DM    = 1024;
static constexpr int NH    = 16;
static constexpr int HD    = 64;
static constexpr int BATCH = 4;
// exp(s/8) = 2^(s * log2(e)/8)
static constexpr float SCL = 0.18033688011112042f;

// async global->LDS, 16B per lane; LDS dest is wave-uniform base + lane*16
__device__ __forceinline__ void gload16(const __bf16* g, __bf16* l) {
  __builtin_amdgcn_global_load_lds((const __attribute__((address_space(1))) void*)g,
                                   (__attribute__((address_space(3))) void*)l, 16, 0, 0);
}

#define PBAR()   asm volatile("s_barrier" ::: "memory")
#define LGKMN(n) asm volatile("s_waitcnt lgkmcnt(" #n ")" ::: "memory")

// ---------------- fp32 -> bf16 convert ----------------
__global__ __launch_bounds__(256) void cvt_kernel(const float* __restrict__ in,
                                                  __bf16* __restrict__ out, int n4) {
  int i = blockIdx.x * 256 + threadIdx.x;
  if (i < n4) {
    float4 v = reinterpret_cast<const float4*>(in)[i];
    bf16x4 o;
    o[0] = (__bf16)v.x; o[1] = (__bf16)v.y; o[2] = (__bf16)v.z; o[3] = (__bf16)v.w;
    reinterpret_cast<bf16x4*>(out)[i] = o;
  }
}

// 4 weight matrices in one launch (blockIdx.y selects)
__global__ __launch_bounds__(256) void cvt4_kernel(
    const float* __restrict__ a, const float* __restrict__ bsrc,
    const float* __restrict__ c, const float* __restrict__ d,
    __bf16* __restrict__ oa, __bf16* __restrict__ ob,
    __bf16* __restrict__ oc, __bf16* __restrict__ od, int n4) {
  const float* src = (blockIdx.y == 0) ? a : (blockIdx.y == 1) ? bsrc
                    : (blockIdx.y == 2) ? c : d;
  __bf16* dst = (blockIdx.y == 0) ? oa : (blockIdx.y == 1) ? ob
               : (blockIdx.y == 2) ? oc : od;
  int i = blockIdx.x * 256 + threadIdx.x;
  if (i < n4) {
    float4 v = reinterpret_cast<const float4*>(src)[i];
    bf16x4 o;
    o[0] = (__bf16)v.x; o[1] = (__bf16)v.y; o[2] = (__bf16)v.z; o[3] = (__bf16)v.w;
    reinterpret_cast<bf16x4*>(dst)[i] = o;
  }
}

// ---------------- QKV GEMM: 256x192, BK=64, 8 waves, read-ahead 4-phase ----------------
// R13: ds_reads issued ONE phase ahead with counted lgkm (R9 schedule, now
// register-feasible at 192: acc 96 AGPR + ~120 VGPR <= 256/wave budget).
//  preloop: read afl,bfl(t0)[12]
//  ph1: R bfh(t)[2];              bar; lgkm(2); Q1 afl*bfl (16)
//  ph2: R afh(t)[8]; G Bn0,n1;    bar; lgkm(8); Q2 afl*bfh (8)
//  ph3: G Bn2,Ah0;                bar; lgkm(0); Q3 afh*bfl (16)
//  ph4: G Ah1; vmcnt(7); bar; R afl,bfl(t+1)[12]; Q4 afh*bfh (8)
// vmcnt(7): the 7 newest = t+2's stages; per-wave drain + PBAR makes t+1's
// LDS data block-visible before the ph4 reads.
__global__ __launch_bounds__(512, 2) void gemm_qkv_kernel(
    const __bf16* __restrict__ A, const __bf16* __restrict__ Wqkv,
    const float* __restrict__ b0, const float* __restrict__ b1,
    const float* __restrict__ b2, __bf16* __restrict__ QKVp) {
  __shared__ __align__(16) __bf16 lA[2 * 256 * 64];   // 64 KB
  __shared__ __align__(16) __bf16 lB[2 * 192 * 64];   // 48 KB
  const int flat = blockIdx.x;                 // 0..511
  const int xcd = flat & 7, idx = flat >> 3;   // idx 0..63
  const int mi = xcd * 4 + (idx & 3);          // 0..31
  const int nig = idx >> 2;                    // 0..15
  const int i0 = mi * 256, o0 = nig * 192;

  const int tid = threadIdx.x;
  const int l = tid & 63, lr = l & 15, lg = l >> 4;
  const int w = tid >> 6;
  const int wr = w >> 2, wc = w & 3;           // wave: rows wr*128, cols wc*48

  f32x4 acc[8][3];
  const f32x4 fzero = {0.f, 0.f, 0.f, 0.f};
#pragma unroll
  for (int mm = 0; mm < 8; ++mm)
#pragma unroll
    for (int ni = 0; ni < 3; ++ni) acc[mm][ni] = fzero;

  const int s_row = tid >> 3;                  // 0..63
  const int s_cc  = tid & 7;
  const __bf16* Ab = A + (size_t)i0 * DM;
  const __bf16* Wb = Wqkv + (size_t)o0 * DM;

  auto stageA = [&](int buf, int kt, int h) {
#pragma unroll
    for (int rr = 0; rr < 2; ++rr) {
      int row = h * 128 + rr * 64 + s_row;
      gload16(Ab + (size_t)row * DM + kt * 64 + ((s_cc ^ (row & 7)) << 3),
              lA + buf * 16384 + (h * 128 + rr * 64) * 64 + tid * 8);
    }
  };
  auto stageB = [&](int buf, int kt, int n) {
    int row = n * 64 + s_row;
    gload16(Wb + (size_t)row * DM + kt * 64 + ((s_cc ^ (row & 7)) << 3),
            lB + buf * 12288 + n * 4096 + tid * 8);
  };
  auto rdA = [&](const __bf16* base, int row, int ks) {
    int chunk = (ks * 4 + lg) ^ (row & 7);
    return *(const bf16x8*)(base + row * 64 + chunk * 8);
  };

  const int NT = DM / 64;                      // 16 K-tiles

  // prologue: stage tiles 0,1 (7 gloads each); vmcnt(7) -> tile 0 ready
#pragma unroll
  for (int h = 0; h < 2; ++h) stageA(0, 0, h);
#pragma unroll
  for (int n = 0; n < 3; ++n) stageB(0, 0, n);
#pragma unroll
  for (int h = 0; h < 2; ++h) stageA(1, 1, h);
#pragma unroll
  for (int n = 0; n < 3; ++n) stageB(1, 1, n);
  asm volatile("s_waitcnt vmcnt(7)" ::: "memory");
  PBAR();

  bf16x8 afl[4][2], afh[4][2], bfl[2][2], bfh[2];
#pragma unroll
  for (int mm = 0; mm < 4; ++mm)
#pragma unroll
    for (int ks = 0; ks < 2; ++ks)
      afl[mm][ks] = rdA(lA, wr * 128 + mm * 16 + lr, ks);
#pragma unroll
  for (int ni = 0; ni < 2; ++ni)
#pragma unroll
    for (int ks = 0; ks < 2; ++ks)
      bfl[ni][ks] = rdA(lB, wc * 48 + ni * 16 + lr, ks);

  for (int t = 0; t < NT; ++t) {
    const int cur = t & 1;
    const __bf16* cA = lA + cur * 16384;
    const __bf16* cB = lB + cur * 12288;
    const __bf16* nA = lA + (cur ^ 1) * 16384;
    const __bf16* nB = lB + (cur ^ 1) * 12288;
    const bool pre = (t + 2 < NT);
    const bool hasnext = (t + 1 < NT);

    // ---- ph1: issue bfh(t); Q1 = afl x bfl (16 MFMA) ----
#pragma unroll
    for (int ks = 0; ks < 2; ++ks)
      bfh[ks] = rdA(cB, wc * 48 + 2 * 16 + lr, ks);
    PBAR(); LGKMN(2);
    __builtin_amdgcn_s_setprio(1);
#pragma unroll
    for (int mm = 0; mm < 4; ++mm)
#pragma unroll
      for (int ni = 0; ni < 2; ++ni)
#pragma unroll
        for (int ks = 0; ks < 2; ++ks)
          acc[mm][ni] = __builtin_amdgcn_mfma_f32_16x16x32_bf16(
              afl[mm][ks], bfl[ni][ks], acc[mm][ni], 0, 0, 0);
    __builtin_amdgcn_s_setprio(0);
    PBAR();

    // ---- ph2: issue afh(t); stage Bn0,Bn1(t+2); Q2 = afl x bfh (8) ----
#pragma unroll
    for (int mm = 0; mm < 4; ++mm)
#pragma unroll
      for (int ks = 0; ks < 2; ++ks)
        afh[mm][ks] = rdA(cA, wr * 128 + (mm + 4) * 16 + lr, ks);
    if (pre) { stageB(cur, t + 2, 0); stageB(cur, t + 2, 1); }
    PBAR(); LGKMN(8);
    __builtin_amdgcn_s_setprio(1);
#pragma unroll
    for (int mm = 0; mm < 4; ++mm)
#pragma unroll
      for (int ks = 0; ks < 2; ++ks)
        acc[mm][2] = __builtin_amdgcn_mfma_f32_16x16x32_bf16(
            afl[mm][ks], bfh[ks], acc[mm][2], 0, 0, 0);
    __builtin_amdgcn_s_setprio(0);
    PBAR();

    // ---- ph3: stage Bn2,Ah0(t+2); Q3 = afh x bfl (16) ----
    if (pre) { stageB(cur, t + 2, 2); stageA(cur, t + 2, 0); }
    PBAR(); LGKMN(0);
    __builtin_amdgcn_s_setprio(1);
#pragma unroll
    for (int mm = 0; mm < 4; ++mm)
#pragma unroll
      for (int ni = 0; ni < 2; ++ni)
#pragma unroll
        for (int ks = 0; ks < 2; ++ks)
          acc[mm + 4][ni] = __builtin_amdgcn_mfma_f32_16x16x32_bf16(
              afh[mm][ks], bfl[ni][ks], acc[mm + 4][ni], 0, 0, 0);
    __builtin_amdgcn_s_setprio(0);
    PBAR();

    // ---- ph4: stage Ah1(t+2); counted vmcnt; read t+1 afl/bfl; Q4 = afh x bfh (8) ----
    if (pre) stageA(cur, t + 2, 1);
    if (pre)                asm volatile("s_waitcnt vmcnt(7)" ::: "memory");
    else if (hasnext)       asm volatile("s_waitcnt vmcnt(0)" ::: "memory");
    PBAR();
    if (hasnext) {
#pragma unroll
      for (int mm = 0; mm < 4; ++mm)
#pragma unroll
        for (int ks = 0; ks < 2; ++ks)
          afl[mm][ks] = rdA(nA, wr * 128 + mm * 16 + lr, ks);
#pragma unroll
      for (int ni = 0; ni < 2; ++ni)
#pragma unroll
        for (int ks = 0; ks < 2; ++ks)
          bfl[ni][ks] = rdA(nB, wc * 48 + ni * 16 + lr, ks);
    }
    __builtin_amdgcn_s_setprio(1);
#pragma unroll
    for (int mm = 0; mm < 4; ++mm)
#pragma unroll
      for (int ks = 0; ks < 2; ++ks)
        acc[mm + 4][2] = __builtin_amdgcn_mfma_f32_16x16x32_bf16(
            afh[mm][ks], bfh[ks], acc[mm + 4][2], 0, 0, 0);
    __builtin_amdgcn_s_setprio(0);
    PBAR();
  }

#pragma unroll
  for (int ni = 0; ni < 3; ++ni) {
    int col = o0 + wc * 48 + ni * 16 + lr;     // global col in [0,3072)
    int z = col >> 10, cin = col & 1023;       // uniform z per 16-col group
    const float* bp = (z == 0) ? b0 : (z == 1) ? b1 : b2;
    float bb = bp[cin];
    __bf16* O = QKVp + (size_t)z * 8192 * DM;
#pragma unroll
    for (int mm = 0; mm < 8; ++mm) {
      int row = i0 + wr * 128 + mm * 16 + lg * 4;
#pragma unroll
      for (int r = 0; r < 4; ++r)
        O[(size_t)(row + r) * DM + cin] = (__bf16)(acc[mm][ni][r] + bb);
    }
  }
}

// ---------------- out-proj GEMM: 128x256 tile, grid 256 ----------------
template <typename OUT_T>
__device__ __forceinline__ void gemm_body2(
    const __bf16* __restrict__ A, const __bf16* __restrict__ W,
    const float* __restrict__ bias, OUT_T* __restrict__ C,
    int i0, int o0, __bf16* lA, __bf16* lB) {
  const int tid = threadIdx.x;          // 0..511
  const int l = tid & 63, lr = l & 15, lg = l >> 4;
  const int w = tid >> 6;
  const int wr = w >> 2, wc = w & 3;

  f32x4 acc[4][4];
  const f32x4 fzero = {0.f, 0.f, 0.f, 0.f};
#pragma unroll
  for (int mi = 0; mi < 4; ++mi)
#pragma unroll
    for (int ni = 0; ni < 4; ++ni) acc[mi][ni] = fzero;

  const int s_row = tid >> 3;
  const int s_cc  = tid & 7;
  const int NT = DM / 64;  // 16

  {
#pragma unroll
    for (int n = 0; n < 2; ++n) {
      int row = n * 64 + s_row;
      gload16(A + (size_t)(i0 + row) * DM + ((s_cc ^ (row & 7)) << 3),
              lA + n * 4096 + tid * 8);
    }
#pragma unroll
    for (int n = 0; n < 4; ++n) {
      int row = n * 64 + s_row;
      gload16(W + (size_t)(o0 + row) * DM + ((s_cc ^ (row & 7)) << 3),
              lB + n * 4096 + tid * 8);
    }
  }
  asm volatile("s_waitcnt vmcnt(0)" ::: "memory");
  __syncthreads();

  for (int t = 0; t < NT; ++t) {
    const int cur = t & 1;
    if (t + 1 < NT) {
      const int k0 = (t + 1) * 64;
      const int nxt = cur ^ 1;
#pragma unroll
      for (int n = 0; n < 2; ++n) {
        int row = n * 64 + s_row;
        gload16(A + (size_t)(i0 + row) * DM + k0 + ((s_cc ^ (row & 7)) << 3),
                lA + nxt * 8192 + n * 4096 + tid * 8);
      }
#pragma unroll
      for (int n = 0; n < 4; ++n) {
        int row = n * 64 + s_row;
        gload16(W + (size_t)(o0 + row) * DM + k0 + ((s_cc ^ (row & 7)) << 3),
                lB + nxt * 16384 + n * 4096 + tid * 8);
      }
    }

    const __bf16* cA = lA + cur * 8192;
    const __bf16* cB = lB + cur * 16384;

    bf16x8 af[4][2], bf_[2][2];
#pragma unroll
    for (int mi = 0; mi < 4; ++mi)
#pragma unroll
      for (int ks = 0; ks < 2; ++ks) {
        int row = wr * 64 + mi * 16 + lr;
        int chunk = (ks * 4 + lg) ^ (row & 7);
        af[mi][ks] = *(const bf16x8*)(cA + row * 64 + chunk * 8);
      }
#pragma unroll
    for (int ni = 0; ni < 2; ++ni)
#pragma unroll
      for (int ks = 0; ks < 2; ++ks) {
        int row = wc * 64 + ni * 16 + lr;
        int chunk = (ks * 4 + lg) ^ (row & 7);
        bf_[ni][ks] = *(const bf16x8*)(cB + row * 64 + chunk * 8);
      }
    __builtin_amdgcn_s_setprio(1);
#pragma unroll
    for (int mi = 0; mi < 4; ++mi)
#pragma unroll
      for (int ni = 0; ni < 2; ++ni)
#pragma unroll
        for (int ks = 0; ks < 2; ++ks)
          acc[mi][ni] = __builtin_amdgcn_mfma_f32_16x16x32_bf16(
              af[mi][ks], bf_[ni][ks], acc[mi][ni], 0, 0, 0);
    __builtin_amdgcn_s_setprio(0);

#pragma unroll
    for (int ni = 0; ni < 2; ++ni)
#pragma unroll
      for (int ks = 0; ks < 2; ++ks) {
        int row = wc * 64 + (ni + 2) * 16 + lr;
        int chunk = (ks * 4 + lg) ^ (row & 7);
        bf_[ni][ks] = *(const bf16x8*)(cB + row * 64 + chunk * 8);
      }
    __builtin_amdgcn_s_setprio(1);
#pragma unroll
    for (int mi = 0; mi < 4; ++mi)
#pragma unroll
      for (int ni = 0; ni < 2; ++ni)
#pragma unroll
        for (int ks = 0; ks < 2; ++ks)
          acc[mi][ni + 2] = __builtin_amdgcn_mfma_f32_16x16x32_bf16(
              af[mi][ks], bf_[ni][ks], acc[mi][ni + 2], 0, 0, 0);
    __builtin_amdgcn_s_setprio(0);

    if (t + 1 < NT) {
      asm volatile("s_waitcnt vmcnt(0)" ::: "memory");
      __syncthreads();
    }
  }

#pragma unroll
  for (int ni = 0; ni < 4; ++ni) {
    int col = o0 + wc * 64 + ni * 16 + lr;
    float bb = bias[col];
#pragma unroll
    for (int mi = 0; mi < 4; ++mi) {
      int row = i0 + wr * 64 + mi * 16 + lg * 4;
#pragma unroll
      for (int r = 0; r < 4; ++r)
        C[(size_t)(row + r) * DM + col] = (OUT_T)(acc[mi][ni][r] + bb);
    }
  }
}

// Output GEMM: grid 256 = 64 mi * 4 ni (exactly 1 block/CU), XCD-grouped.
__global__ __launch_bounds__(512, 2) void gemm_out_kernel(
    const __bf16* __restrict__ A, const __bf16* __restrict__ W,
    const float* __restrict__ bias, float* __restrict__ C) {
  __shared__ __align__(16) __bf16 lA[2 * 128 * 64];
  __shared__ __align__(16) __bf16 lB[2 * 256 * 64];
  const int flat = blockIdx.x;
  const int xcd = flat & 7, idx = flat >> 3;       // idx 0..31
  const int mi = xcd * 8 + (idx & 7);              // 0..63
  const int ni = idx >> 3;                         // 0..3
  gemm_body2<float>(A, W, bias, C, mi * 128, ni * 256, lA, lB);
}

// ---------------- pass B (FUSED-Q): both kt {31-bx, bx} share one Q stream ----------------
// kt1 = 31-bx (q-range subset), kt2 = bx. One jj-loop over kt2's chunks; each
// Q chunk loaded ONCE feeds both kf sets (-26% global loads, same MFMA; MFMA
// work constant 132 chunk-sets/block). flat grid 1024, XCD-grouped.
__global__ __launch_bounds__(256) void colstats_kernel(
    const __bf16* __restrict__ Q, const __bf16* __restrict__ K,
    const __bf16* __restrict__ V, __bf16* __restrict__ VT) {
  const int flat = blockIdx.x;
  const int wid = (flat & 7) * 128 + (flat >> 3);  // 0..1023
  const int g = wid >> 4, bx = wid & 15;
  const int h = g & 15, b = g >> 4;
  const int tid = threadIdx.x;
  const int w = tid >> 6, l = tid & 63, lr = l & 15, lg = l >> 4;
  const size_t base = (size_t)b * TSEQ * DM + (size_t)h * HD;

  const int kt1 = 31 - bx, kt2 = bx;
  const int k01 = kt1 * 64, k02 = kt2 * 64;

  __shared__ float part[4][64];
  __shared__ float invc[64];

  bf16x8 kf1[4][2], kf2[4][2];
#pragma unroll
  for (int ct = 0; ct < 4; ++ct)
#pragma unroll
    for (int ks = 0; ks < 2; ++ks) {
      kf1[ct][ks] = *(const bf16x8*)(K + base + (size_t)(k01 + ct * 16 + lr) * DM +
                                     ks * 32 + lg * 8);
      kf2[ct][ks] = *(const bf16x8*)(K + base + (size_t)(k02 + ct * 16 + lr) * DM +
                                     ks * 32 + lg * 8);
    }

  float csum1[4] = {0.f, 0.f, 0.f, 0.f};
  float csum2[4] = {0.f, 0.f, 0.f, 0.f};
  const int nchunks = (TSEQ - k02) >> 4;   // kt2's (larger) range
  for (int jj = w; jj < nchunks; jj += 4) {
    const int qrow = k02 + jj * 16;
    bf16x8 a0 = *(const bf16x8*)(Q + base + (size_t)(qrow + lr) * DM + lg * 8);
    bf16x8 a1 = *(const bf16x8*)(Q + base + (size_t)(qrow + lr) * DM + 32 + lg * 8);

    // kt2 contribution (always active)
    {
      const bool interior = (jj >= 4);
#pragma unroll
      for (int ct = 0; ct < 4; ++ct) {
        f32x4 s = {0.f, 0.f, 0.f, 0.f};
        s = __builtin_amdgcn_mfma_f32_16x16x32_bf16(a0, kf2[ct][0], s, 0, 0, 0);
        s = __builtin_amdgcn_mfma_f32_16x16x32_bf16(a1, kf2[ct][1], s, 0, 0, 0);
        if (interior) {
#pragma unroll
          for (int r = 0; r < 4; ++r) csum2[ct] += __builtin_amdgcn_exp2f(s[r] * SCL);
        } else {
#pragma unroll
          for (int r = 0; r < 4; ++r) {
            int ql = jj * 16 + lg * 4 + r;
            int kl = ct * 16 + lr;
            float e = __builtin_amdgcn_exp2f(s[r] * SCL);
            csum2[ct] += (ql >= kl) ? e : 0.f;
          }
        }
      }
    }
    // kt1 contribution (active when qrow reaches its diagonal)
    if (qrow >= k01) {
      const bool interior = (qrow >= k01 + 64);
#pragma unroll
      for (int ct = 0; ct < 4; ++ct) {
        f32x4 s = {0.f, 0.f, 0.f, 0.f};
        s = __builtin_amdgcn_mfma_f32_16x16x32_bf16(a0, kf1[ct][0], s, 0, 0, 0);
        s = __builtin_amdgcn_mfma_f32_16x16x32_bf16(a1, kf1[ct][1], s, 0, 0, 0);
        if (interior) {
#pragma unroll
          for (int r = 0; r < 4; ++r) csum1[ct] += __builtin_amdgcn_exp2f(s[r] * SCL);
        } else {
#pragma unroll
          for (int r = 0; r < 4; ++r) {
            int ql = (qrow - k01) + lg * 4 + r;
            int kl = ct * 16 + lr;
            float e = __builtin_amdgcn_exp2f(s[r] * SCL);
            csum1[ct] += (ql >= kl) ? e : 0.f;
          }
        }
      }
    }
  }

#pragma unroll
  for (int ct = 0; ct < 4; ++ct) {
    csum1[ct] += __shfl_xor(csum1[ct], 16, 64);
    csum1[ct] += __shfl_xor(csum1[ct], 32, 64);
    csum2[ct] += __shfl_xor(csum2[ct], 16, 64);
    csum2[ct] += __shfl_xor(csum2[ct], 32, 64);
  }

  const int d = tid >> 2, gq = tid & 3;
  // ---- epilogue for kt1 ----
  if (l < 16) {
#pragma unroll
    for (int ct = 0; ct < 4; ++ct) part[w][ct * 16 + l] = csum1[ct];
  }
  __syncthreads();
  if (tid < 64)
    invc[tid] = 1.0f / (part[0][tid] + part[1][tid] + part[2][tid] + part[3][tid]);
  __syncthreads();
  {
    size_t vtb = (((size_t)(b * NH + h)) * HD + d) * TSEQ + k01 + gq * 16;
#pragma unroll
    for (int kc = 0; kc < 16; kc += 2) {
      int kl = gq * 16 + kc;
      float v0 = (float)V[base + (size_t)(k01 + kl) * DM + d] * invc[kl];
      float v1 = (float)V[base + (size_t)(k01 + kl + 1) * DM + d] * invc[kl + 1];
      bf16x2 o; o[0] = (__bf16)v0; o[1] = (__bf16)v1;
      *(bf16x2*)(VT + vtb + kc) = o;
    }
  }
  __syncthreads();  // invc reads done before overwrite
  // ---- epilogue for kt2 ----
  if (l < 16) {
#pragma unroll
    for (int ct = 0; ct < 4; ++ct) part[w][ct * 16 + l] = csum2[ct];
  }
  __syncthreads();
  if (tid < 64)
    invc[tid] = 1.0f / (part[0][tid] + part[1][tid] + part[2][tid] + part[3][tid]);
  __syncthreads();
  {
    size_t vtb = (((size_t)(b * NH + h)) * HD + d) * TSEQ + k02 + gq * 16;
#pragma unroll
    for (int kc = 0; kc < 16; kc += 2) {
      int kl = gq * 16 + kc;
      float v0 = (float)V[base + (size_t)(k02 + kl) * DM + d] * invc[kl];
      float v1 = (float)V[base + (size_t)(k02 + kl + 1) * DM + d] * invc[kl + 1];
      bf16x2 o; o[0] = (__bf16)v0; o[1] = (__bf16)v1;
      *(bf16x2*)(VT + vtb + kc) = o;
    }
  }
}

// XOR swizzle (involution) on element index of a [64][64] bf16 tile
__device__ __forceinline__ int swz(int e) { return e ^ (((e >> 6) & 7) << 3); }

// ---------------- pass C (FUSED x2): q-tiles {31-bx, bx} in ONE K-loop ----------------
// Single-buffered (TLP covers latency: 39KB LDS -> 4 blocks/CU = 16 waves).
__global__ __launch_bounds__(256, 4) void ctx_kernel(
    const __bf16* __restrict__ Q, const __bf16* __restrict__ K,
    const __bf16* __restrict__ VT, __bf16* __restrict__ CTX) {
  __shared__ __align__(16) __bf16 lK[4096];
  __shared__ __align__(16) __bf16 lV[4096];
  __shared__ __align__(16) __bf16 lP[8][16 * 88];   // [wave + 4*tile]
  const int flat = blockIdx.x;
  const int wid = (flat & 7) * 128 + (flat >> 3);  // 0..1023
  const int g = wid >> 4, bx = wid & 15;
  const int h = g & 15, b = g >> 4;
  const int tid = threadIdx.x;
  const int w = tid >> 6, l = tid & 63, lr = l & 15, lg = l >> 4;
  const size_t base = (size_t)b * TSEQ * DM + (size_t)h * HD;
  const size_t vtb = ((size_t)(b * NH + h)) * HD * TSEQ;
  __bf16* pw1 = &lP[w][0];
  __bf16* pw2 = &lP[w + 4][0];

  const int qt1 = 31 - bx, qt2 = bx;   // qt1 >= 16 > qt2 always
  const int q01 = qt1 * 64, q02 = qt2 * 64;

  const int srow = w * 8 + (l >> 3);
  const int scol = (((l & 7) ^ (l >> 3)) << 3);

  bf16x8 qf1[2], qf2[2];
#pragma unroll
  for (int ks = 0; ks < 2; ++ks) {
    qf1[ks] = *(const bf16x8*)(Q + base + (size_t)(q01 + w * 16 + lr) * DM + ks * 32 + lg * 8);
    qf2[ks] = *(const bf16x8*)(Q + base + (size_t)(q02 + w * 16 + lr) * DM + ks * 32 + lg * 8);
  }

  f32x4 acc1[4], acc2[4];
  const f32x4 fzero = {0.f, 0.f, 0.f, 0.f};
#pragma unroll
  for (int dt = 0; dt < 4; ++dt) { acc1[dt] = fzero; acc2[dt] = fzero; }

  for (int kt = 0; kt <= qt1; ++kt) {
    const int k0 = kt * 64;
    const bool two = (kt <= qt2);
    __syncthreads();   // prior iter's LDS reads done before overwrite
#pragma unroll
    for (int n = 0; n < 2; ++n) {
      gload16(K + base + (size_t)(k0 + n * 32 + srow) * DM + scol,
              lK + n * 2048 + w * 512);
      gload16(VT + vtb + (size_t)(n * 32 + srow) * TSEQ + k0 + scol,
              lV + n * 2048 + w * 512);
    }
    asm volatile("s_waitcnt vmcnt(0)" ::: "memory");
    __syncthreads();

    const bool diag1 = (kt == qt1), diag2 = (kt == qt2);
#pragma unroll
    for (int ct = 0; ct < 4; ++ct) {
      bf16x8 kb[2];
#pragma unroll
      for (int ks = 0; ks < 2; ++ks) {
        int e = (ct * 16 + lr) * 64 + ks * 32 + lg * 8;
        kb[ks] = *(const bf16x8*)(lK + swz(e));
      }
      {
        f32x4 s = {0.f, 0.f, 0.f, 0.f};
        s = __builtin_amdgcn_mfma_f32_16x16x32_bf16(kb[0], qf1[0], s, 0, 0, 0);
        s = __builtin_amdgcn_mfma_f32_16x16x32_bf16(kb[1], qf1[1], s, 0, 0, 0);
        bf16x4 pk;
        if (diag1) {
#pragma unroll
          for (int r = 0; r < 4; ++r) {
            int ql = w * 16 + lr, kl = ct * 16 + lg * 4 + r;
            pk[r] = (__bf16)((ql >= kl) ? __builtin_amdgcn_exp2f(s[r] * SCL) : 0.f);
          }
        } else {
#pragma unroll
          for (int r = 0; r < 4; ++r)
            pk[r] = (__bf16)__builtin_amdgcn_exp2f(s[r] * SCL);
        }
        *(bf16x4*)(pw1 + lr * 88 + ct * 16 + lg * 4) = pk;
      }
      if (two) {
        f32x4 s = {0.f, 0.f, 0.f, 0.f};
        s = __builtin_amdgcn_mfma_f32_16x16x32_bf16(kb[0], qf2[0], s, 0, 0, 0);
        s = __builtin_amdgcn_mfma_f32_16x16x32_bf16(kb[1], qf2[1], s, 0, 0, 0);
        bf16x4 pk;
        if (diag2) {
#pragma unroll
          for (int r = 0; r < 4; ++r) {
            int ql = w * 16 + lr, kl = ct * 16 + lg * 4 + r;
            pk[r] = (__bf16)((ql >= kl) ? __builtin_amdgcn_exp2f(s[r] * SCL) : 0.f);
          }
        } else {
#pragma unroll
          for (int r = 0; r < 4; ++r)
            pk[r] = (__bf16)__builtin_amdgcn_exp2f(s[r] * SCL);
        }
        *(bf16x4*)(pw2 + lr * 88 + ct * 16 + lg * 4) = pk;
      }
    }
    asm volatile("" ::: "memory");  // same-wave DS in-order: P writes before reads

    bf16x8 pa1[2], pa2[2];
#pragma unroll
    for (int ks = 0; ks < 2; ++ks)
      pa1[ks] = *(const bf16x8*)(pw1 + lr * 88 + ks * 32 + lg * 8);
    if (two) {
#pragma unroll
      for (int ks = 0; ks < 2; ++ks)
        pa2[ks] = *(const bf16x8*)(pw2 + lr * 88 + ks * 32 + lg * 8);
    }
#pragma unroll
    for (int dt = 0; dt < 4; ++dt) {
#pragma unroll
      for (int ks = 0; ks < 2; ++ks) {
        int e = (dt * 16 + lr) * 64 + ks * 32 + lg * 8;
        bf16x8 vb8 = *(const bf16x8*)(lV + swz(e));   // shared by both tiles
        acc1[dt] = __builtin_amdgcn_mfma_f32_16x16x32_bf16(pa1[ks], vb8, acc1[dt], 0, 0, 0);
        if (two)
          acc2[dt] = __builtin_amdgcn_mfma_f32_16x16x32_bf16(pa2[ks], vb8, acc2[dt], 0, 0, 0);
      }
    }
  }

#pragma unroll
  for (int dt = 0; dt < 4; ++dt)
#pragma unroll
    for (int r = 0; r < 4; ++r) {
      CTX[base + (size_t)(q01 + w * 16 + lg * 4 + r) * DM + dt * 16 + lr] = (__bf16)acc1[dt][r];
      CTX[base + (size_t)(q02 + w * 16 + lg * 4 + r) * DM + dt * 16 + lr] = (__bf16)acc2[dt][r];
    }
}

extern "C" void kernel_launch(void* const* d_in, const int* in_sizes, int n_in,
                              void* d_out, int out_size, void* d_ws, size_t ws_size,
                              hipStream_t stream) {
  const float* q  = (const float*)d_in[0];
  const float* Wq = (const float*)d_in[3];
  const float* bq = (const float*)d_in[4];
  const float* Wk = (const float*)d_in[5];
  const float* bk = (const float*)d_in[6];
  const float* Wv = (const float*)d_in[7];
  const float* bv = (const float*)d_in[8];
  const float* Wo = (const float*)d_in[9];
  const float* bo = (const float*)d_in[10];
  float* out = (float*)d_out;

  const size_t NTOK = (size_t)BATCH * TSEQ;  // 8192
  char* ws = (char*)d_ws;
  __bf16* qb   = (__bf16*)ws; ws += NTOK * DM * 2;      // reused as CTX later
  __bf16* Wqkv = (__bf16*)ws; ws += 3 * (size_t)DM * DM * 2;  // [3][1024][1024]
  __bf16* Wob  = (__bf16*)ws; ws += (size_t)DM * DM * 2;
  __bf16* QKVp = (__bf16*)ws; ws += 3 * NTOK * DM * 2;  // [3][8192][1024]
  __bf16* VT   = (__bf16*)ws; ws += (size_t)BATCH * NH * HD * TSEQ * 2;
  __bf16* CTX = qb;  // qb dead after the QKV GEMM

  __bf16* Qp = QKVp;
  __bf16* Kp = QKVp + NTOK * DM;
  __bf16* Vp = QKVp + 2 * NTOK * DM;

  const int nq4 = (int)(NTOK * DM / 4);
  const int nw4 = DM * DM / 4;
  cvt_kernel<<<(nq4 + 255) / 256, 256, 0, stream>>>(q, qb, nq4);
  cvt4_kernel<<<dim3((nw4 + 255) / 256, 4), 256, 0, stream>>>(
      Wq, Wk, Wv, Wo, Wqkv, Wqkv + (size_t)DM * DM, Wqkv + 2 * (size_t)DM * DM, Wob, nw4);

  gemm_qkv_kernel<<<512, 512, 0, stream>>>(qb, Wqkv, bq, bk, bv, QKVp);

  colstats_kernel<<<1024, 256, 0, stream>>>(Qp, Kp, Vp, VT);
  ctx_kernel<<<1024, 256, 0, stream>>>(Qp, Kp, VT, CTX);

  gemm_out_kernel<<<256, 512, 0, stream>>>(CTX, Wob, bo, out);
}